// Round 1
// baseline (512.893 us; speedup 1.0000x reference)
//
#include <hip/hip_runtime.h>
#include <cstdint>

#define JAX_PARTITIONABLE 1

#define NPTS   4096
#define NBATCH 1024
#define NIT    10

// ---------------- threefry2x32 (exact JAX rounds) ----------------
__host__ __device__ inline uint32_t rotl32(uint32_t v, uint32_t r){ return (v<<r)|(v>>(32u-r)); }

__host__ __device__ inline void tf2x32(uint32_t k0,uint32_t k1,uint32_t x0,uint32_t x1,
                                       uint32_t&o0,uint32_t&o1){
  uint32_t ks2 = k0 ^ k1 ^ 0x1BD11BDAu;
  x0 += k0; x1 += k1;
  x0+=x1; x1=rotl32(x1,13); x1^=x0;
  x0+=x1; x1=rotl32(x1,15); x1^=x0;
  x0+=x1; x1=rotl32(x1,26); x1^=x0;
  x0+=x1; x1=rotl32(x1, 6); x1^=x0;
  x0+=k1; x1+=ks2+1u;
  x0+=x1; x1=rotl32(x1,17); x1^=x0;
  x0+=x1; x1=rotl32(x1,29); x1^=x0;
  x0+=x1; x1=rotl32(x1,16); x1^=x0;
  x0+=x1; x1=rotl32(x1,24); x1^=x0;
  x0+=ks2; x1+=k0+2u;
  x0+=x1; x1=rotl32(x1,13); x1^=x0;
  x0+=x1; x1=rotl32(x1,15); x1^=x0;
  x0+=x1; x1=rotl32(x1,26); x1^=x0;
  x0+=x1; x1=rotl32(x1, 6); x1^=x0;
  x0+=k0; x1+=k1+3u;
  x0+=x1; x1=rotl32(x1,17); x1^=x0;
  x0+=x1; x1=rotl32(x1,29); x1^=x0;
  x0+=x1; x1=rotl32(x1,16); x1^=x0;
  x0+=x1; x1=rotl32(x1,24); x1^=x0;
  x0+=k1; x1+=ks2+4u;
  x0+=x1; x1=rotl32(x1,13); x1^=x0;
  x0+=x1; x1=rotl32(x1,15); x1^=x0;
  x0+=x1; x1=rotl32(x1,26); x1^=x0;
  x0+=x1; x1=rotl32(x1, 6); x1^=x0;
  x0+=ks2; x1+=k0+5u;
  o0=x0; o1=x1;
}

// ---------------- small helpers ----------------
__device__ inline float errsq_f(const float H[9], float x, float y, float kx, float ky){
  float z  = H[6]*x + H[7]*y + H[8];
  float zi = (fabsf(z) > 1e-8f) ? (1.0f/z) : 1.0f;
  float px = (H[0]*x + H[1]*y + H[2])*zi;
  float py = (H[3]*x + H[4]*y + H[5])*zi;
  float dx = px - kx, dy = py - ky;
  return dx*dx + dy*dy;
}

// H = inv(T2) * Hn * T1, then / (H22 + 1e-8). h is the (unit) 9-vector.
__device__ inline void denorm_h(const double h[9], double s1, double m1x, double m1y,
                                double s2, double m2x, double m2y, float out[9]){
  double G[3][3];
  #pragma unroll
  for(int r=0;r<3;r++){
    double h0=h[3*r], h1=h[3*r+1], h2=h[3*r+2];
    G[r][0] = h0*s1;
    G[r][1] = h1*s1;
    G[r][2] = -s1*m1x*h0 - s1*m1y*h1 + h2;
  }
  double Hm[3][3];
  double inv2 = 1.0/s2;
  #pragma unroll
  for(int c=0;c<3;c++){
    Hm[0][c] = G[0][c]*inv2 + m2x*G[2][c];
    Hm[1][c] = G[1][c]*inv2 + m2y*G[2][c];
    Hm[2][c] = G[2][c];
  }
  double invd = 1.0/(Hm[2][2] + 1e-8);
  #pragma unroll
  for(int r=0;r<3;r++)
    #pragma unroll
    for(int c=0;c<3;c++)
      out[3*r+c] = (float)(Hm[r][c]*invd);
}

__device__ inline double det3h(const double* a, const double* b, const double* c){
  return a[0]*(b[1]-c[1]) - a[1]*(b[0]-c[0]) + (b[0]*c[1] - b[1]*c[0]);
}

// ---------------- K0: init + full-set normalization ----------------
__global__ __launch_bounds__(1024) void k_init(const float* __restrict__ kp1,
                                               const float* __restrict__ kp2,
                                               float* stateF, float* nrm,
                                               float* best_inl, float* p1n, float* p2n){
  __shared__ double red[1024];
  const int t = threadIdx.x;
  auto blk_reduce = [&](double v)->double{
    red[t]=v; __syncthreads();
    for(int off=512; off>=1; off>>=1){ if(t<off) red[t]+=red[t+off]; __syncthreads(); }
    double rr = red[0]; __syncthreads(); return rr;
  };
  double sx1=0, sy1=0, sx2=0, sy2=0;
  #pragma unroll
  for(int q=0;q<4;q++){
    int p = t + 1024*q;
    sx1 += (double)kp1[2*p];   sy1 += (double)kp1[2*p+1];
    sx2 += (double)kp2[2*p];   sy2 += (double)kp2[2*p+1];
  }
  double m1x = blk_reduce(sx1)/(double)NPTS;
  double m1y = blk_reduce(sy1)/(double)NPTS;
  double m2x = blk_reduce(sx2)/(double)NPTS;
  double m2y = blk_reduce(sy2)/(double)NPTS;
  double a1=0, a2=0;
  #pragma unroll
  for(int q=0;q<4;q++){
    int p = t + 1024*q;
    double dx1=(double)kp1[2*p]-m1x, dy1=(double)kp1[2*p+1]-m1y;
    double dx2=(double)kp2[2*p]-m2x, dy2=(double)kp2[2*p+1]-m2y;
    a1 += sqrt(dx1*dx1+dy1*dy1);
    a2 += sqrt(dx2*dx2+dy2*dy2);
  }
  double sc1 = blk_reduce(a1)/(double)NPTS;
  double sc2 = blk_reduce(a2)/(double)NPTS;
  double s1 = 1.4142135623730951/(sc1+1e-8);
  double s2 = 1.4142135623730951/(sc2+1e-8);
  if(t==0){
    nrm[0]=(float)s1; nrm[1]=(float)m1x; nrm[2]=(float)m1y;
    nrm[3]=(float)s2; nrm[4]=(float)m2x; nrm[5]=(float)m2y;
    stateF[0]=4.0f;   // best_score init = SAMPLE
    stateF[1]=0.0f;   // done
    for(int j=0;j<9;j++) stateF[2+j]=0.0f;
  }
  #pragma unroll
  for(int q=0;q<4;q++){
    int p = t + 1024*q;
    p1n[2*p]   = (float)(s1*((double)kp1[2*p]  -m1x));
    p1n[2*p+1] = (float)(s1*((double)kp1[2*p+1]-m1y));
    p2n[2*p]   = (float)(s2*((double)kp2[2*p]  -m2x));
    p2n[2*p+1] = (float)(s2*((double)kp2[2*p+1]-m2y));
    best_inl[p] = 0.0f;
  }
}

// ---------------- K1: uniform + top_k(4) sampling ----------------
__device__ inline void ins4(uint64_t b[4], uint64_t k){
  if(k > b[0]){ b[3]=b[2]; b[2]=b[1]; b[1]=b[0]; b[0]=k; }
  else if(k > b[1]){ b[3]=b[2]; b[2]=b[1]; b[1]=k; }
  else if(k > b[2]){ b[3]=b[2]; b[2]=k; }
  else if(k > b[3]){ b[3]=k; }
}

__global__ __launch_bounds__(256) void k_sample(const float* stateF,
                                                uint32_t key0, uint32_t key1,
                                                int* __restrict__ idxs){
  if(stateF[1] != 0.0f) return;
  const int r = blockIdx.x;
  const int t = threadIdx.x;
  __shared__ uint64_t ls[256][4];
  uint64_t b[4] = {0ull,0ull,0ull,0ull};
  #pragma unroll
  for(int j=0;j<16;j++){
    int c = t*16 + j;
    uint32_t f = (uint32_t)(r*NPTS + c);
    uint32_t a0,a1; uint32_t bits;
#if JAX_PARTITIONABLE
    tf2x32(key0,key1, 0u, f, a0,a1);
    bits = a0 ^ a1;
#else
    const uint32_t HALF = (uint32_t)(NBATCH*NPTS/2);
    if(f < HALF){ tf2x32(key0,key1, f, f+HALF, a0,a1); bits = a0; }
    else        { tf2x32(key0,key1, f-HALF, f, a0,a1); bits = a1; }
#endif
    uint64_t v = (uint64_t)((bits>>9) + 1u);
    uint64_t key = (v<<12) | (uint64_t)(4095 - c);
    ins4(b, key);
  }
  ls[t][0]=b[0]; ls[t][1]=b[1]; ls[t][2]=b[2]; ls[t][3]=b[3];
  __syncthreads();
  for(int off=128; off>=1; off>>=1){
    if(t < off){
      uint64_t o0=ls[t+off][0], o1=ls[t+off][1], o2=ls[t+off][2], o3=ls[t+off][3];
      ins4(b,o0); ins4(b,o1); ins4(b,o2); ins4(b,o3);
      ls[t][0]=b[0]; ls[t][1]=b[1]; ls[t][2]=b[2]; ls[t][3]=b[3];
    }
    __syncthreads();
  }
  if(t==0){
    idxs[r*4+0] = 4095 - (int)(b[0] & 0xFFFull);
    idxs[r*4+1] = 4095 - (int)(b[1] & 0xFFFull);
    idxs[r*4+2] = 4095 - (int)(b[2] & 0xFFFull);
    idxs[r*4+3] = 4095 - (int)(b[3] & 0xFFFull);
  }
}

// ---------------- K2: 1024 four-point DLT models ----------------
__global__ __launch_bounds__(256) void k_models(const float* stateF,
                                                const int* __restrict__ idxs,
                                                const float* __restrict__ kp1,
                                                const float* __restrict__ kp2,
                                                float* __restrict__ models,
                                                float* __restrict__ flags){
  if(stateF[1] != 0.0f) return;
  const int m = blockIdx.x*blockDim.x + threadIdx.x;
  if(m >= NBATCH) return;
  double P1[4][2], P2[4][2];
  #pragma unroll
  for(int k=0;k<4;k++){
    int id = idxs[m*4+k];
    P1[k][0]=(double)kp1[2*id]; P1[k][1]=(double)kp1[2*id+1];
    P2[k][0]=(double)kp2[2*id]; P2[k][1]=(double)kp2[2*id+1];
  }
  // validity: det-sign agreement over 4 triplets
  const int TRI[4][3] = {{0,1,2},{0,1,3},{0,2,3},{1,2,3}};
  bool valid = true;
  #pragma unroll
  for(int tq=0;tq<4;tq++){
    double d1 = det3h(P1[TRI[tq][0]],P1[TRI[tq][1]],P1[TRI[tq][2]]);
    double d2 = det3h(P2[TRI[tq][0]],P2[TRI[tq][1]],P2[TRI[tq][2]]);
    int s1 = (d1>0.0)-(d1<0.0), s2 = (d2>0.0)-(d2<0.0);
    if(s1 != s2) valid = false;
  }
  // normalize 4-point sets
  double m1x=0,m1y=0,m2x=0,m2y=0;
  #pragma unroll
  for(int k=0;k<4;k++){ m1x+=P1[k][0]; m1y+=P1[k][1]; m2x+=P2[k][0]; m2y+=P2[k][1]; }
  m1x*=0.25; m1y*=0.25; m2x*=0.25; m2y*=0.25;
  double sc1=0, sc2=0;
  #pragma unroll
  for(int k=0;k<4;k++){
    double dx=P1[k][0]-m1x, dy=P1[k][1]-m1y; sc1 += sqrt(dx*dx+dy*dy);
    dx=P2[k][0]-m2x; dy=P2[k][1]-m2y;        sc2 += sqrt(dx*dx+dy*dy);
  }
  sc1*=0.25; sc2*=0.25;
  double s1n = 1.4142135623730951/(sc1+1e-8);
  double s2n = 1.4142135623730951/(sc2+1e-8);
  // build A (8x9)
  double A[8][9];
  #pragma unroll
  for(int k=0;k<4;k++){
    double X = s1n*(P1[k][0]-m1x), Y = s1n*(P1[k][1]-m1y);
    double XX= s2n*(P2[k][0]-m2x), YY= s2n*(P2[k][1]-m2y);
    A[k][0]=0; A[k][1]=0; A[k][2]=0;
    A[k][3]=-X; A[k][4]=-Y; A[k][5]=-1.0;
    A[k][6]=YY*X; A[k][7]=YY*Y; A[k][8]=YY;
    A[4+k][0]=X; A[4+k][1]=Y; A[4+k][2]=1.0;
    A[4+k][3]=0; A[4+k][4]=0; A[4+k][5]=0;
    A[4+k][6]=-XX*X; A[4+k][7]=-XX*Y; A[4+k][8]=-XX;
  }
  // Gaussian elimination w/ partial pivoting -> null vector
  int pivcol[8]; bool used[9];
  for(int j=0;j<9;j++) used[j]=false;
  int r=0;
  for(int c=0;c<9 && r<8;c++){
    int pr=-1; double best=1e-12;
    for(int i=r;i<8;i++){ double a=fabs(A[i][c]); if(a>best){best=a; pr=i;} }
    if(pr<0) continue;
    if(pr!=r){ for(int j=0;j<9;j++){ double tmp=A[r][j]; A[r][j]=A[pr][j]; A[pr][j]=tmp; } }
    double inv = 1.0/A[r][c];
    for(int i=r+1;i<8;i++){
      double f = A[i][c]*inv;
      if(f!=0.0){ for(int j=c;j<9;j++) A[i][j] -= f*A[r][j]; A[i][c]=0.0; }
    }
    pivcol[r]=c; used[c]=true; r++;
  }
  int fc=0; while(fc<9 && used[fc]) fc++;
  double h[9];
  for(int j=0;j<9;j++) h[j]=0.0;
  if(fc<9) h[fc]=1.0; else h[8]=1.0;
  for(int k=r-1;k>=0;k--){
    int pc=pivcol[k];
    double s=0.0;
    for(int j=0;j<9;j++) if(j!=pc) s += A[k][j]*h[j];
    h[pc] = -s / A[k][pc];
  }
  double n2=0.0;
  for(int j=0;j<9;j++) n2 += h[j]*h[j];
  double invn = 1.0/sqrt(n2);
  for(int j=0;j<9;j++) h[j]*=invn;
  float Hf[9];
  denorm_h(h, s1n,m1x,m1y, s2n,m2x,m2y, Hf);
  bool diag_ok = (fminf(fminf(fabsf(Hf[0]),fabsf(Hf[4])),fabsf(Hf[8])) > 1e-4f);
  #pragma unroll
  for(int j=0;j<9;j++) models[m*9+j]=Hf[j];
  flags[m] = (valid && diag_ok) ? 1.0f : 0.0f;
}

// ---------------- K3: verify (scores) ----------------
__global__ __launch_bounds__(256) void k_score(const float* stateF,
                                               const float* __restrict__ models,
                                               const float* __restrict__ flags,
                                               const float* __restrict__ kp1,
                                               const float* __restrict__ kp2,
                                               float* __restrict__ scores){
  if(stateF[1] != 0.0f) return;
  const int b = blockIdx.x;
  const int t = threadIdx.x;
  __shared__ int red[256];
  float H[9];
  #pragma unroll
  for(int j=0;j<9;j++) H[j]=models[b*9+j];
  int cnt=0;
  for(int p=t; p<NPTS; p+=256){
    float e = errsq_f(H, kp1[2*p], kp1[2*p+1], kp2[2*p], kp2[2*p+1]);
    cnt += (e <= 2.0f) ? 1 : 0;
  }
  red[t]=cnt; __syncthreads();
  for(int off=128; off>=1; off>>=1){ if(t<off) red[t]+=red[t+off]; __syncthreads(); }
  if(t==0) scores[b] = (flags[b]!=0.0f) ? (float)red[0] : -1.0f;
}

// ---------------- K5: argmax + polish + state update ----------------
__global__ __launch_bounds__(512) void k_polish(float* stateF, const float* nrm,
                                                const float* __restrict__ scores,
                                                const float* __restrict__ models,
                                                const float* __restrict__ kp1,
                                                const float* __restrict__ kp2,
                                                const float* __restrict__ p1n,
                                                const float* __restrict__ p2n,
                                                float* __restrict__ best_inl,
                                                int iter){
  if(stateF[1] != 0.0f) return;
  const int t = threadIdx.x;
  __shared__ uint64_t red[512];
  __shared__ float partials[8][45];
  __shared__ float sM[45];
  __shared__ float sModel[9];
  __shared__ float curH[9];
  __shared__ unsigned char inlb[2][NPTS];

  // ---- argmax over 1024 scores (first-index tie-break) ----
  {
    float sA = scores[t], sB = scores[t+512];
    uint64_t kA = ((uint64_t)(uint32_t)(int)(sA + 2.0f) << 12) | (uint64_t)(1023 - t);
    uint64_t kB = ((uint64_t)(uint32_t)(int)(sB + 2.0f) << 12) | (uint64_t)(1023 - (t+512));
    red[t] = (kA >= kB) ? kA : kB;
  }
  __syncthreads();
  for(int off=256; off>=1; off>>=1){
    if(t<off){ uint64_t o=red[t+off]; if(o>red[t]) red[t]=o; }
    __syncthreads();
  }
  const int bi = 1023 - (int)(red[0] & 0xFFFull);
  const float selScore = (float)((int)(red[0] >> 12)) - 2.0f;
  __syncthreads();

  const float bestScore = stateF[0];
  const bool improve = (selScore > bestScore);
  if(!improve) return;

  if(t<9) sModel[t] = models[bi*9+t];
  __syncthreads();

  // cache this thread's 8 points
  float U1[8],V1[8],U2[8],V2[8],X1[8],Y1[8],X2[8],Y2[8];
  #pragma unroll
  for(int q=0;q<8;q++){
    int p = t + 512*q;
    U1[q]=kp1[2*p]; V1[q]=kp1[2*p+1];
    U2[q]=kp2[2*p]; V2[q]=kp2[2*p+1];
    X1[q]=p1n[2*p]; Y1[q]=p1n[2*p+1];
    X2[q]=p2n[2*p]; Y2[q]=p2n[2*p+1];
  }
  // initial inliers of selected model
  {
    float H[9];
    #pragma unroll
    for(int j=0;j<9;j++) H[j]=sModel[j];
    #pragma unroll
    for(int q=0;q<8;q++){
      int p = t + 512*q;
      float e = errsq_f(H, U1[q],V1[q],U2[q],V2[q]);
      inlb[0][p] = (e <= 2.0f) ? 1 : 0;
    }
  }
  __syncthreads();

  int cur = 0;
  float score = selScore;
  bool active = true;
  float wreg[8];

  const double ns1=(double)nrm[0], nm1x=(double)nrm[1], nm1y=(double)nrm[2];
  const double ns2=(double)nrm[3], nm2x=(double)nrm[4], nm2y=(double)nrm[5];

  auto DLT = [&](){
    float part[45];
    #pragma unroll
    for(int k=0;k<45;k++) part[k]=0.0f;
    #pragma unroll
    for(int q=0;q<8;q++){
      float w = wreg[q];
      if(w != 0.0f){
        float x1=X1[q], y1=Y1[q], x2=X2[q], y2=Y2[q];
        float a[9] = {0.f,0.f,0.f, -x1,-y1,-1.f, y2*x1, y2*y1, y2};
        float b[9] = {x1,y1,1.f, 0.f,0.f,0.f, -x2*x1, -x2*y1, -x2};
        int idx=0;
        #pragma unroll
        for(int i=0;i<9;i++){
          #pragma unroll
          for(int j=0;j<=i;j++){
            part[idx] += w*(a[i]*a[j] + b[i]*b[j]);
            idx++;
          }
        }
      }
    }
    #pragma unroll
    for(int off=32; off>=1; off>>=1){
      #pragma unroll
      for(int k=0;k<45;k++) part[k] += __shfl_down(part[k], off, 64);
    }
    const int wv = t>>6, lane = t&63;
    if(lane==0){
      #pragma unroll
      for(int k=0;k<45;k++) partials[wv][k]=part[k];
    }
    __syncthreads();
    if(t<45){
      float acc=0.0f;
      #pragma unroll
      for(int w8=0; w8<8; w8++) acc += partials[w8][t];
      sM[t]=acc;
    }
    __syncthreads();
    if(t==0){
      // f64 Cholesky of AtWA from sM (lower-tri, row-major packed)
      double L[9][9];
      #pragma unroll
      for(int j=0;j<9;j++){
        double d = (double)sM[j*(j+1)/2 + j];
        #pragma unroll
        for(int k=0;k<9;k++) if(k<j) d -= L[j][k]*L[j][k];
        if(d < 1e-280) d = 1e-280;
        double Ljj = sqrt(d); L[j][j]=Ljj;
        double inv = 1.0/Ljj;
        #pragma unroll
        for(int i=j+1;i<9;i++){
          double s = (double)sM[i*(i+1)/2 + j];
          #pragma unroll
          for(int k=0;k<9;k++) if(k<j) s -= L[i][k]*L[j][k];
          L[i][j] = s*inv;
        }
      }
      // inverse iteration -> smallest-eigenvalue eigenvector
      double v[9];
      #pragma unroll
      for(int i=0;i<9;i++) v[i]=1.0;
      for(int itn=0; itn<10; itn++){
        double y[9];
        #pragma unroll
        for(int j=0;j<9;j++){
          double s=v[j];
          #pragma unroll
          for(int k=0;k<9;k++) if(k<j) s -= L[j][k]*y[k];
          y[j]=s/L[j][j];
        }
        #pragma unroll
        for(int j=8;j>=0;j--){
          double s=y[j];
          #pragma unroll
          for(int k=0;k<9;k++) if(k>j) s -= L[k][j]*v[k];
          v[j]=s/L[j][j];
        }
        double n2=0.0;
        #pragma unroll
        for(int i=0;i<9;i++) n2 += v[i]*v[i];
        double invn = 1.0/sqrt(n2);
        #pragma unroll
        for(int i=0;i<9;i++) v[i]*=invn;
      }
      denorm_h(v, ns1,nm1x,nm1y, ns2,nm2x,nm2y, curH);
    }
    __syncthreads();
  };

  for(int lo=0; lo<5; lo++){
    // iterated DLT: first with 0/1 weights
    #pragma unroll
    for(int q=0;q<8;q++){ int p=t+512*q; wreg[q] = inlb[cur][p] ? 1.0f : 0.0f; }
    DLT();
    for(int itp=0; itp<4; itp++){
      float H[9];
      #pragma unroll
      for(int j=0;j<9;j++) H[j]=curH[j];
      #pragma unroll
      for(int q=0;q<8;q++){
        int p=t+512*q;
        float e   = errsq_f(H, U1[q],V1[q],U2[q],V2[q]);
        float err = sqrtf(e + 1e-8f);
        wreg[q] = inlb[cur][p] ? expf(-err/18.0f) : 0.0f;
      }
      DLT();
    }
    // verify polished model
    float scoreLo;
    {
      float H[9];
      #pragma unroll
      for(int j=0;j<9;j++) H[j]=curH[j];
      int c=0;
      #pragma unroll
      for(int q=0;q<8;q++){
        int p=t+512*q;
        float e = errsq_f(H, U1[q],V1[q],U2[q],V2[q]);
        unsigned char bb = (e <= 2.0f) ? 1 : 0;
        inlb[cur^1][p] = bb;
        c += bb;
      }
      red[t]=(uint64_t)c; __syncthreads();
      for(int off=256; off>=1; off>>=1){ if(t<off) red[t]+=red[t+off]; __syncthreads(); }
      scoreLo = (float)(int)(red[0]);
      __syncthreads();
    }
    bool better = active && (scoreLo > score);
    if(better){
      if(t<9) sModel[t]=curH[t];
      cur ^= 1;
      score = scoreLo;
    }
    active = better;
    __syncthreads();
    if(!active) break;
  }

  // commit state
  if(t<9) stateF[2+t] = sModel[t];
  #pragma unroll
  for(int q=0;q<8;q++){ int p=t+512*q; best_inl[p] = inlb[cur][p] ? 1.0f : 0.0f; }
  if(t==0){
    stateF[0] = score;
    float ratio = floorf(score) / 4096.0f;
    float r2 = ratio*ratio, r4 = r2*r2;
    float q  = 1.0f - r4;
    q = fminf(fmaxf(q, 1e-12f), (float)(1.0 - 1e-12));
    float max_samp = (score >= 4096.0f) ? 1.0f : (logf(0.01f)/logf(q));
    stateF[1] = (((float)((iter+1)*NBATCH)) >= floorf(max_samp)) ? 1.0f : 0.0f;
  }
}

// ---------------- K6: writeout ----------------
__global__ __launch_bounds__(1024) void k_out(const float* stateF, const float* best_inl,
                                              float* __restrict__ out, int out_size){
  const int t = threadIdx.x;
  if(t<9 && t<out_size) out[t] = stateF[2+t];
  #pragma unroll
  for(int q=0;q<4;q++){
    int p = t + 1024*q, o = 9 + p;
    if(o < out_size) out[o] = best_inl[p];
  }
}

// ---------------- host ----------------
static void host_keys(uint32_t* K0h, uint32_t* K1h){
#if JAX_PARTITIONABLE
  for(int i=0;i<10;i++){ uint32_t a,b; tf2x32(0u,42u,0u,(uint32_t)i,a,b); K0h[i]=a; K1h[i]=b; }
#else
  uint32_t arr[20];
  for(int j=0;j<10;j++){ uint32_t a,b; tf2x32(0u,42u,(uint32_t)j,(uint32_t)(j+10),a,b); arr[j]=a; arr[j+10]=b; }
  for(int i=0;i<10;i++){ K0h[i]=arr[2*i]; K1h[i]=arr[2*i+1]; }
#endif
}

extern "C" void kernel_launch(void* const* d_in, const int* in_sizes, int n_in,
                              void* d_out, int out_size, void* d_ws, size_t ws_size,
                              hipStream_t stream) {
  const float* kp1 = (const float*)d_in[0];
  const float* kp2 = (const float*)d_in[1];
  float* out = (float*)d_out;
  float* ws  = (float*)d_ws;

  // ws layout (floats)
  float* stateF   = ws + 0;      // 16: [0]=best_score [1]=done [2..10]=best_model
  float* nrm      = ws + 16;     // 8
  float* best_inl = ws + 32;     // 4096
  float* p1n      = ws + 4128;   // 8192
  float* p2n      = ws + 12320;  // 8192
  float* scores   = ws + 20512;  // 1024
  float* flags    = ws + 21536;  // 1024
  float* models   = ws + 22560;  // 9216
  int*   idxs     = (int*)(ws + 31776); // 4096 ints

  uint32_t K0h[10], K1h[10];
  host_keys(K0h, K1h);

  k_init<<<1, 1024, 0, stream>>>(kp1, kp2, stateF, nrm, best_inl, p1n, p2n);
  for(int i=0;i<NIT;i++){
    k_sample<<<NBATCH, 256, 0, stream>>>(stateF, K0h[i], K1h[i], idxs);
    k_models<<<NBATCH/256, 256, 0, stream>>>(stateF, idxs, kp1, kp2, models, flags);
    k_score <<<NBATCH, 256, 0, stream>>>(stateF, models, flags, kp1, kp2, scores);
    k_polish<<<1, 512, 0, stream>>>(stateF, nrm, scores, models, kp1, kp2, p1n, p2n, best_inl, i);
  }
  k_out<<<1, 1024, 0, stream>>>(stateF, best_inl, out, out_size);
}

// Round 2
// 258.662 us; speedup vs baseline: 1.9829x; 1.9829x over previous
//
#include <hip/hip_runtime.h>
#include <cstdint>

#define JAX_PARTITIONABLE 1

#define NPTS   4096
#define NBATCH 1024
#define NIT    10

// ---------------- threefry2x32 (exact JAX rounds) ----------------
__host__ __device__ inline uint32_t rotl32(uint32_t v, uint32_t r){ return (v<<r)|(v>>(32u-r)); }

__host__ __device__ inline void tf2x32(uint32_t k0,uint32_t k1,uint32_t x0,uint32_t x1,
                                       uint32_t&o0,uint32_t&o1){
  uint32_t ks2 = k0 ^ k1 ^ 0x1BD11BDAu;
  x0 += k0; x1 += k1;
  x0+=x1; x1=rotl32(x1,13); x1^=x0;
  x0+=x1; x1=rotl32(x1,15); x1^=x0;
  x0+=x1; x1=rotl32(x1,26); x1^=x0;
  x0+=x1; x1=rotl32(x1, 6); x1^=x0;
  x0+=k1; x1+=ks2+1u;
  x0+=x1; x1=rotl32(x1,17); x1^=x0;
  x0+=x1; x1=rotl32(x1,29); x1^=x0;
  x0+=x1; x1=rotl32(x1,16); x1^=x0;
  x0+=x1; x1=rotl32(x1,24); x1^=x0;
  x0+=ks2; x1+=k0+2u;
  x0+=x1; x1=rotl32(x1,13); x1^=x0;
  x0+=x1; x1=rotl32(x1,15); x1^=x0;
  x0+=x1; x1=rotl32(x1,26); x1^=x0;
  x0+=x1; x1=rotl32(x1, 6); x1^=x0;
  x0+=k0; x1+=k1+3u;
  x0+=x1; x1=rotl32(x1,17); x1^=x0;
  x0+=x1; x1=rotl32(x1,29); x1^=x0;
  x0+=x1; x1=rotl32(x1,16); x1^=x0;
  x0+=x1; x1=rotl32(x1,24); x1^=x0;
  x0+=k1; x1+=ks2+4u;
  x0+=x1; x1=rotl32(x1,13); x1^=x0;
  x0+=x1; x1=rotl32(x1,15); x1^=x0;
  x0+=x1; x1=rotl32(x1,26); x1^=x0;
  x0+=x1; x1=rotl32(x1, 6); x1^=x0;
  x0+=ks2; x1+=k0+5u;
  o0=x0; o1=x1;
}

// ---------------- small helpers ----------------
__device__ inline float errsq_f(const float H[9], float x, float y, float kx, float ky){
  float z  = H[6]*x + H[7]*y + H[8];
  float zi = (fabsf(z) > 1e-8f) ? (1.0f/z) : 1.0f;
  float px = (H[0]*x + H[1]*y + H[2])*zi;
  float py = (H[3]*x + H[4]*y + H[5])*zi;
  float dx = px - kx, dy = py - ky;
  return dx*dx + dy*dy;
}

// H = inv(T2) * Hn * T1, then / (H22 + 1e-8). h is the 9-vector (any scale).
__device__ inline void denorm_h(const double h[9], double s1, double m1x, double m1y,
                                double s2, double m2x, double m2y, float out[9]){
  double G[3][3];
  #pragma unroll
  for(int r=0;r<3;r++){
    double h0=h[3*r], h1=h[3*r+1], h2=h[3*r+2];
    G[r][0] = h0*s1;
    G[r][1] = h1*s1;
    G[r][2] = -s1*m1x*h0 - s1*m1y*h1 + h2;
  }
  double Hm[3][3];
  double inv2 = 1.0/s2;
  #pragma unroll
  for(int c=0;c<3;c++){
    Hm[0][c] = G[0][c]*inv2 + m2x*G[2][c];
    Hm[1][c] = G[1][c]*inv2 + m2y*G[2][c];
    Hm[2][c] = G[2][c];
  }
  double invd = 1.0/(Hm[2][2] + 1e-8);
  #pragma unroll
  for(int r=0;r<3;r++)
    #pragma unroll
    for(int c=0;c<3;c++)
      out[3*r+c] = (float)(Hm[r][c]*invd);
}

__device__ inline double det3h(const double* a, const double* b, const double* c){
  return a[0]*(b[1]-c[1]) - a[1]*(b[0]-c[0]) + (b[0]*c[1] - b[1]*c[0]);
}

// ---------------- K0: init + full-set normalization ----------------
__global__ __launch_bounds__(1024) void k_init(const float* __restrict__ kp1,
                                               const float* __restrict__ kp2,
                                               float* stateF, float* nrm,
                                               float* best_inl, float* p1n, float* p2n){
  __shared__ double red[1024];
  const int t = threadIdx.x;
  auto blk_reduce = [&](double v)->double{
    red[t]=v; __syncthreads();
    for(int off=512; off>=1; off>>=1){ if(t<off) red[t]+=red[t+off]; __syncthreads(); }
    double rr = red[0]; __syncthreads(); return rr;
  };
  double sx1=0, sy1=0, sx2=0, sy2=0;
  #pragma unroll
  for(int q=0;q<4;q++){
    int p = t + 1024*q;
    sx1 += (double)kp1[2*p];   sy1 += (double)kp1[2*p+1];
    sx2 += (double)kp2[2*p];   sy2 += (double)kp2[2*p+1];
  }
  double m1x = blk_reduce(sx1)/(double)NPTS;
  double m1y = blk_reduce(sy1)/(double)NPTS;
  double m2x = blk_reduce(sx2)/(double)NPTS;
  double m2y = blk_reduce(sy2)/(double)NPTS;
  double a1=0, a2=0;
  #pragma unroll
  for(int q=0;q<4;q++){
    int p = t + 1024*q;
    double dx1=(double)kp1[2*p]-m1x, dy1=(double)kp1[2*p+1]-m1y;
    double dx2=(double)kp2[2*p]-m2x, dy2=(double)kp2[2*p+1]-m2y;
    a1 += sqrt(dx1*dx1+dy1*dy1);
    a2 += sqrt(dx2*dx2+dy2*dy2);
  }
  double sc1 = blk_reduce(a1)/(double)NPTS;
  double sc2 = blk_reduce(a2)/(double)NPTS;
  double s1 = 1.4142135623730951/(sc1+1e-8);
  double s2 = 1.4142135623730951/(sc2+1e-8);
  if(t==0){
    nrm[0]=(float)s1; nrm[1]=(float)m1x; nrm[2]=(float)m1y;
    nrm[3]=(float)s2; nrm[4]=(float)m2x; nrm[5]=(float)m2y;
    stateF[0]=4.0f;   // best_score init = SAMPLE
    stateF[1]=0.0f;   // done
    for(int j=0;j<9;j++) stateF[2+j]=0.0f;
  }
  #pragma unroll
  for(int q=0;q<4;q++){
    int p = t + 1024*q;
    p1n[2*p]   = (float)(s1*((double)kp1[2*p]  -m1x));
    p1n[2*p+1] = (float)(s1*((double)kp1[2*p+1]-m1y));
    p2n[2*p]   = (float)(s2*((double)kp2[2*p]  -m2x));
    p2n[2*p+1] = (float)(s2*((double)kp2[2*p+1]-m2y));
    best_inl[p] = 0.0f;
  }
}

// ---------------- K1: uniform + top_k(4) sampling ----------------
__device__ inline void ins4(uint64_t b[4], uint64_t k){
  if(k > b[0]){ b[3]=b[2]; b[2]=b[1]; b[1]=b[0]; b[0]=k; }
  else if(k > b[1]){ b[3]=b[2]; b[2]=b[1]; b[1]=k; }
  else if(k > b[2]){ b[3]=b[2]; b[2]=k; }
  else if(k > b[3]){ b[3]=k; }
}

__global__ __launch_bounds__(256) void k_sample(const float* stateF,
                                                uint32_t key0, uint32_t key1,
                                                int* __restrict__ idxs){
  if(stateF[1] != 0.0f) return;
  const int r = blockIdx.x;
  const int t = threadIdx.x;
  __shared__ uint64_t ls[256][4];
  uint64_t b[4] = {0ull,0ull,0ull,0ull};
  #pragma unroll
  for(int j=0;j<16;j++){
    int c = t*16 + j;
    uint32_t f = (uint32_t)(r*NPTS + c);
    uint32_t a0,a1; uint32_t bits;
#if JAX_PARTITIONABLE
    tf2x32(key0,key1, 0u, f, a0,a1);
    bits = a0 ^ a1;
#else
    const uint32_t HALF = (uint32_t)(NBATCH*NPTS/2);
    if(f < HALF){ tf2x32(key0,key1, f, f+HALF, a0,a1); bits = a0; }
    else        { tf2x32(key0,key1, f-HALF, f, a0,a1); bits = a1; }
#endif
    uint64_t v = (uint64_t)((bits>>9) + 1u);
    uint64_t key = (v<<12) | (uint64_t)(4095 - c);
    ins4(b, key);
  }
  ls[t][0]=b[0]; ls[t][1]=b[1]; ls[t][2]=b[2]; ls[t][3]=b[3];
  __syncthreads();
  for(int off=128; off>=1; off>>=1){
    if(t < off){
      uint64_t o0=ls[t+off][0], o1=ls[t+off][1], o2=ls[t+off][2], o3=ls[t+off][3];
      ins4(b,o0); ins4(b,o1); ins4(b,o2); ins4(b,o3);
      ls[t][0]=b[0]; ls[t][1]=b[1]; ls[t][2]=b[2]; ls[t][3]=b[3];
    }
    __syncthreads();
  }
  if(t==0){
    idxs[r*4+0] = 4095 - (int)(b[0] & 0xFFFull);
    idxs[r*4+1] = 4095 - (int)(b[1] & 0xFFFull);
    idxs[r*4+2] = 4095 - (int)(b[2] & 0xFFFull);
    idxs[r*4+3] = 4095 - (int)(b[3] & 0xFFFull);
  }
}

// ---------------- K2: 1024 four-point DLT models ----------------
__global__ __launch_bounds__(256) void k_models(const float* stateF,
                                                const int* __restrict__ idxs,
                                                const float* __restrict__ kp1,
                                                const float* __restrict__ kp2,
                                                float* __restrict__ models,
                                                float* __restrict__ flags){
  if(stateF[1] != 0.0f) return;
  const int m = blockIdx.x*blockDim.x + threadIdx.x;
  if(m >= NBATCH) return;
  double P1[4][2], P2[4][2];
  #pragma unroll
  for(int k=0;k<4;k++){
    int id = idxs[m*4+k];
    P1[k][0]=(double)kp1[2*id]; P1[k][1]=(double)kp1[2*id+1];
    P2[k][0]=(double)kp2[2*id]; P2[k][1]=(double)kp2[2*id+1];
  }
  // validity: det-sign agreement over 4 triplets
  const int TRI[4][3] = {{0,1,2},{0,1,3},{0,2,3},{1,2,3}};
  bool valid = true;
  #pragma unroll
  for(int tq=0;tq<4;tq++){
    double d1 = det3h(P1[TRI[tq][0]],P1[TRI[tq][1]],P1[TRI[tq][2]]);
    double d2 = det3h(P2[TRI[tq][0]],P2[TRI[tq][1]],P2[TRI[tq][2]]);
    int s1 = (d1>0.0)-(d1<0.0), s2 = (d2>0.0)-(d2<0.0);
    if(s1 != s2) valid = false;
  }
  // normalize 4-point sets
  double m1x=0,m1y=0,m2x=0,m2y=0;
  #pragma unroll
  for(int k=0;k<4;k++){ m1x+=P1[k][0]; m1y+=P1[k][1]; m2x+=P2[k][0]; m2y+=P2[k][1]; }
  m1x*=0.25; m1y*=0.25; m2x*=0.25; m2y*=0.25;
  double sc1=0, sc2=0;
  #pragma unroll
  for(int k=0;k<4;k++){
    double dx=P1[k][0]-m1x, dy=P1[k][1]-m1y; sc1 += sqrt(dx*dx+dy*dy);
    dx=P2[k][0]-m2x; dy=P2[k][1]-m2y;        sc2 += sqrt(dx*dx+dy*dy);
  }
  sc1*=0.25; sc2*=0.25;
  double s1n = 1.4142135623730951/(sc1+1e-8);
  double s2n = 1.4142135623730951/(sc2+1e-8);
  // build A (8x9)
  double A[8][9];
  #pragma unroll
  for(int k=0;k<4;k++){
    double X = s1n*(P1[k][0]-m1x), Y = s1n*(P1[k][1]-m1y);
    double XX= s2n*(P2[k][0]-m2x), YY= s2n*(P2[k][1]-m2y);
    A[k][0]=0; A[k][1]=0; A[k][2]=0;
    A[k][3]=-X; A[k][4]=-Y; A[k][5]=-1.0;
    A[k][6]=YY*X; A[k][7]=YY*Y; A[k][8]=YY;
    A[4+k][0]=X; A[4+k][1]=Y; A[4+k][2]=1.0;
    A[4+k][3]=0; A[4+k][4]=0; A[4+k][5]=0;
    A[4+k][6]=-XX*X; A[4+k][7]=-XX*Y; A[4+k][8]=-XX;
  }
  // Gaussian elimination w/ partial pivoting -> null vector
  int pivcol[8]; bool used[9];
  for(int j=0;j<9;j++) used[j]=false;
  int r=0;
  for(int c=0;c<9 && r<8;c++){
    int pr=-1; double best=1e-12;
    for(int i=r;i<8;i++){ double a=fabs(A[i][c]); if(a>best){best=a; pr=i;} }
    if(pr<0) continue;
    if(pr!=r){ for(int j=0;j<9;j++){ double tmp=A[r][j]; A[r][j]=A[pr][j]; A[pr][j]=tmp; } }
    double inv = 1.0/A[r][c];
    for(int i=r+1;i<8;i++){
      double f = A[i][c]*inv;
      if(f!=0.0){ for(int j=c;j<9;j++) A[i][j] -= f*A[r][j]; A[i][c]=0.0; }
    }
    pivcol[r]=c; used[c]=true; r++;
  }
  int fc=0; while(fc<9 && used[fc]) fc++;
  double h[9];
  for(int j=0;j<9;j++) h[j]=0.0;
  if(fc<9) h[fc]=1.0; else h[8]=1.0;
  for(int k=r-1;k>=0;k--){
    int pc=pivcol[k];
    double s=0.0;
    for(int j=0;j<9;j++) if(j!=pc) s += A[k][j]*h[j];
    h[pc] = -s / A[k][pc];
  }
  double n2=0.0;
  for(int j=0;j<9;j++) n2 += h[j]*h[j];
  double invn = 1.0/sqrt(n2);
  for(int j=0;j<9;j++) h[j]*=invn;
  float Hf[9];
  denorm_h(h, s1n,m1x,m1y, s2n,m2x,m2y, Hf);
  bool diag_ok = (fminf(fminf(fabsf(Hf[0]),fabsf(Hf[4])),fabsf(Hf[8])) > 1e-4f);
  #pragma unroll
  for(int j=0;j<9;j++) models[m*9+j]=Hf[j];
  flags[m] = (valid && diag_ok) ? 1.0f : 0.0f;
}

// ---------------- K3: verify (scores) ----------------
__global__ __launch_bounds__(256) void k_score(const float* stateF,
                                               const float* __restrict__ models,
                                               const float* __restrict__ flags,
                                               const float* __restrict__ kp1,
                                               const float* __restrict__ kp2,
                                               float* __restrict__ scores){
  if(stateF[1] != 0.0f) return;
  const int b = blockIdx.x;
  const int t = threadIdx.x;
  __shared__ int red[256];
  float H[9];
  #pragma unroll
  for(int j=0;j<9;j++) H[j]=models[b*9+j];
  int cnt=0;
  for(int p=t; p<NPTS; p+=256){
    float e = errsq_f(H, kp1[2*p], kp1[2*p+1], kp2[2*p], kp2[2*p+1]);
    cnt += (e <= 2.0f) ? 1 : 0;
  }
  red[t]=cnt; __syncthreads();
  for(int off=128; off>=1; off>>=1){ if(t<off) red[t]+=red[t+off]; __syncthreads(); }
  if(t==0) scores[b] = (flags[b]!=0.0f) ? (float)red[0] : -1.0f;
}

// ---------------- K5: argmax + polish + state update ----------------
// AtWA has only 24 distinct values due to the a/b row block structure:
//   a = [0, -u, y2*u], b = [u, 0, -x2*u], u=(x1,y1,1)
//   AtWA = [[S0, 0, -S1],[0, S0, -S2],[-S1, -S2, S3]] (3x3 sym blocks)
// with S0=sum w*M, S1=sum w*x2*M, S2=sum w*y2*M, S3=sum w*(x2^2+y2^2)*M,
// M = packed sym moment [x1^2, x1y1, y1^2, x1, y1, 1].
__global__ __launch_bounds__(512) void k_polish(float* stateF, const float* nrm,
                                                const float* __restrict__ scores,
                                                const float* __restrict__ models,
                                                const float* __restrict__ kp1,
                                                const float* __restrict__ kp2,
                                                const float* __restrict__ p1n,
                                                const float* __restrict__ p2n,
                                                float* __restrict__ best_inl,
                                                int iter){
  if(stateF[1] != 0.0f) return;
  const int t = threadIdx.x;
  __shared__ uint64_t red[512];
  __shared__ float partials[8][24];
  __shared__ float sM[24];
  __shared__ float sModel[9];
  __shared__ float curH[9];
  __shared__ unsigned char inlb[2][NPTS];

  // ---- argmax over 1024 scores (first-index tie-break) ----
  {
    float sA = scores[t], sB = scores[t+512];
    uint64_t kA = ((uint64_t)(uint32_t)(int)(sA + 2.0f) << 12) | (uint64_t)(1023 - t);
    uint64_t kB = ((uint64_t)(uint32_t)(int)(sB + 2.0f) << 12) | (uint64_t)(1023 - (t+512));
    red[t] = (kA >= kB) ? kA : kB;
  }
  __syncthreads();
  for(int off=256; off>=1; off>>=1){
    if(t<off){ uint64_t o=red[t+off]; if(o>red[t]) red[t]=o; }
    __syncthreads();
  }
  const int bi = 1023 - (int)(red[0] & 0xFFFull);
  const float selScore = (float)((int)(red[0] >> 12)) - 2.0f;
  __syncthreads();

  const float bestScore = stateF[0];
  const bool improve = (selScore > bestScore);
  if(!improve) return;

  if(t<9) sModel[t] = models[bi*9+t];
  __syncthreads();

  // cache this thread's 8 points
  float U1[8],V1[8],U2[8],V2[8],X1[8],Y1[8],X2[8],Y2[8];
  #pragma unroll
  for(int q=0;q<8;q++){
    int p = t + 512*q;
    U1[q]=kp1[2*p]; V1[q]=kp1[2*p+1];
    U2[q]=kp2[2*p]; V2[q]=kp2[2*p+1];
    X1[q]=p1n[2*p]; Y1[q]=p1n[2*p+1];
    X2[q]=p2n[2*p]; Y2[q]=p2n[2*p+1];
  }
  // initial inliers of selected model
  {
    float H[9];
    #pragma unroll
    for(int j=0;j<9;j++) H[j]=sModel[j];
    #pragma unroll
    for(int q=0;q<8;q++){
      int p = t + 512*q;
      float e = errsq_f(H, U1[q],V1[q],U2[q],V2[q]);
      inlb[0][p] = (e <= 2.0f) ? 1 : 0;
    }
  }
  __syncthreads();

  int cur = 0;
  float score = selScore;
  bool active = true;
  float wreg[8];

  const double ns1=(double)nrm[0], nm1x=(double)nrm[1], nm1y=(double)nrm[2];
  const double ns2=(double)nrm[3], nm2x=(double)nrm[4], nm2y=(double)nrm[5];

  auto DLT = [&](){
    float part[24];
    #pragma unroll
    for(int k=0;k<24;k++) part[k]=0.0f;
    #pragma unroll
    for(int q=0;q<8;q++){
      float w = wreg[q];
      float x=X1[q], y=Y1[q], x2=X2[q], y2=Y2[q];
      float wx = w*x, wy = w*y;
      float m0=wx*x, m1=wx*y, m2=wy*y, m3=wx, m4=wy, m5=w;
      float s3 = x2*x2 + y2*y2;
      part[0]+=m0; part[1]+=m1; part[2]+=m2; part[3]+=m3; part[4]+=m4; part[5]+=m5;
      part[6]+=x2*m0; part[7]+=x2*m1; part[8]+=x2*m2; part[9]+=x2*m3; part[10]+=x2*m4; part[11]+=x2*m5;
      part[12]+=y2*m0; part[13]+=y2*m1; part[14]+=y2*m2; part[15]+=y2*m3; part[16]+=y2*m4; part[17]+=y2*m5;
      part[18]+=s3*m0; part[19]+=s3*m1; part[20]+=s3*m2; part[21]+=s3*m3; part[22]+=s3*m4; part[23]+=s3*m5;
    }
    #pragma unroll
    for(int off=32; off>=1; off>>=1){
      #pragma unroll
      for(int k=0;k<24;k++) part[k] += __shfl_down(part[k], off, 64);
    }
    const int wv = t>>6, lane = t&63;
    if(lane==0){
      #pragma unroll
      for(int k=0;k<24;k++) partials[wv][k]=part[k];
    }
    __syncthreads();
    if(t<24){
      float acc=0.0f;
      #pragma unroll
      for(int w8=0; w8<8; w8++) acc += partials[w8][t];
      sM[t]=acc;
    }
    __syncthreads();
    if(t==0){
      // reconstruct 9x9 lower triangle from 24 sums (f64)
      double S[24];
      #pragma unroll
      for(int k=0;k<24;k++) S[k]=(double)sM[k];
      // sym3 expansion indices for packed [x2,xy,y2,x,y,1]:
      // U[0][0]=s0 U[1][0]=s1 U[1][1]=s2 U[2][0]=s3 U[2][1]=s4 U[2][2]=s5
      double A[9][9];
      #pragma unroll
      for(int i=0;i<9;i++)
        #pragma unroll
        for(int j=0;j<9;j++) A[i][j]=0.0;
      auto put_sym_lower = [&](int r0,int c0,const double* s,double sgn){
        A[r0+0][c0+0]=sgn*s[0];
        A[r0+1][c0+0]=sgn*s[1]; A[r0+1][c0+1]=sgn*s[2];
        A[r0+2][c0+0]=sgn*s[3]; A[r0+2][c0+1]=sgn*s[4]; A[r0+2][c0+2]=sgn*s[5];
      };
      auto put_sym_full = [&](int r0,int c0,const double* s,double sgn){
        A[r0+0][c0+0]=sgn*s[0]; A[r0+0][c0+1]=sgn*s[1]; A[r0+0][c0+2]=sgn*s[3];
        A[r0+1][c0+0]=sgn*s[1]; A[r0+1][c0+1]=sgn*s[2]; A[r0+1][c0+2]=sgn*s[4];
        A[r0+2][c0+0]=sgn*s[3]; A[r0+2][c0+1]=sgn*s[4]; A[r0+2][c0+2]=sgn*s[5];
      };
      put_sym_lower(0,0, S+0,  1.0);   // (0:3,0:3) = S0
      put_sym_lower(3,3, S+0,  1.0);   // (3:6,3:6) = S0
      put_sym_full (6,0, S+6, -1.0);   // (6:9,0:3) = -S1
      put_sym_full (6,3, S+12,-1.0);   // (6:9,3:6) = -S2
      put_sym_lower(6,6, S+18, 1.0);   // (6:9,6:9) = S3

      // f64 Cholesky with reciprocal diagonals
      double L[9][9], invd[9];
      #pragma unroll
      for(int j=0;j<9;j++){
        double d = A[j][j];
        #pragma unroll
        for(int k=0;k<9;k++) if(k<j) d -= L[j][k]*L[j][k];
        if(d < 1e-280) d = 1e-280;
        double Ljj = sqrt(d); L[j][j]=Ljj; invd[j]=1.0/Ljj;
        #pragma unroll
        for(int i=j+1;i<9;i++){
          double s = A[i][j];
          #pragma unroll
          for(int k=0;k<9;k++) if(k<j) s -= L[i][k]*L[j][k];
          L[i][j] = s*invd[j];
        }
      }
      // 2 inverse iterations (no per-iter normalization; one max-abs rescale)
      double v[9], y[9];
      #pragma unroll
      for(int i=0;i<9;i++) v[i]=1.0;
      #pragma unroll
      for(int itn=0; itn<2; itn++){
        #pragma unroll
        for(int j=0;j<9;j++){
          double s=v[j];
          #pragma unroll
          for(int k=0;k<9;k++) if(k<j) s -= L[j][k]*y[k];
          y[j]=s*invd[j];
        }
        #pragma unroll
        for(int j=8;j>=0;j--){
          double s=y[j];
          #pragma unroll
          for(int k=0;k<9;k++) if(k>j) s -= L[k][j]*v[k];
          v[j]=s*invd[j];
        }
        if(itn==0){
          double mx=0.0;
          #pragma unroll
          for(int i=0;i<9;i++){ double a=fabs(v[i]); if(a>mx) mx=a; }
          double sc = 1.0/(mx + 1e-300);
          #pragma unroll
          for(int i=0;i<9;i++) v[i]*=sc;
        }
      }
      double n2=0.0;
      #pragma unroll
      for(int i=0;i<9;i++) n2 += v[i]*v[i];
      double invn = 1.0/sqrt(n2);
      #pragma unroll
      for(int i=0;i<9;i++) v[i]*=invn;
      denorm_h(v, ns1,nm1x,nm1y, ns2,nm2x,nm2y, curH);
    }
    __syncthreads();
  };

  for(int lo=0; lo<5; lo++){
    // iterated DLT: first with 0/1 weights
    #pragma unroll
    for(int q=0;q<8;q++){ int p=t+512*q; wreg[q] = inlb[cur][p] ? 1.0f : 0.0f; }
    DLT();
    for(int itp=0; itp<4; itp++){
      float H[9];
      #pragma unroll
      for(int j=0;j<9;j++) H[j]=curH[j];
      #pragma unroll
      for(int q=0;q<8;q++){
        int p=t+512*q;
        float e   = errsq_f(H, U1[q],V1[q],U2[q],V2[q]);
        float err = sqrtf(e + 1e-8f);
        wreg[q] = inlb[cur][p] ? expf(-err/18.0f) : 0.0f;
      }
      DLT();
    }
    // verify polished model
    float scoreLo;
    {
      float H[9];
      #pragma unroll
      for(int j=0;j<9;j++) H[j]=curH[j];
      int c=0;
      #pragma unroll
      for(int q=0;q<8;q++){
        int p=t+512*q;
        float e = errsq_f(H, U1[q],V1[q],U2[q],V2[q]);
        unsigned char bb = (e <= 2.0f) ? 1 : 0;
        inlb[cur^1][p] = bb;
        c += bb;
      }
      red[t]=(uint64_t)c; __syncthreads();
      for(int off=256; off>=1; off>>=1){ if(t<off) red[t]+=red[t+off]; __syncthreads(); }
      scoreLo = (float)(int)(red[0]);
      __syncthreads();
    }
    bool better = active && (scoreLo > score);
    if(better){
      if(t<9) sModel[t]=curH[t];
      cur ^= 1;
      score = scoreLo;
    }
    active = better;
    __syncthreads();
    if(!active) break;
  }

  // commit state
  if(t<9) stateF[2+t] = sModel[t];
  #pragma unroll
  for(int q=0;q<8;q++){ int p=t+512*q; best_inl[p] = inlb[cur][p] ? 1.0f : 0.0f; }
  if(t==0){
    stateF[0] = score;
    float ratio = floorf(score) / 4096.0f;
    float r2 = ratio*ratio, r4 = r2*r2;
    float q  = 1.0f - r4;
    q = fminf(fmaxf(q, 1e-12f), (float)(1.0 - 1e-12));
    float max_samp = (score >= 4096.0f) ? 1.0f : (logf(0.01f)/logf(q));
    stateF[1] = (((float)((iter+1)*NBATCH)) >= floorf(max_samp)) ? 1.0f : 0.0f;
  }
}

// ---------------- K6: writeout ----------------
__global__ __launch_bounds__(1024) void k_out(const float* stateF, const float* best_inl,
                                              float* __restrict__ out, int out_size){
  const int t = threadIdx.x;
  if(t<9 && t<out_size) out[t] = stateF[2+t];
  #pragma unroll
  for(int q=0;q<4;q++){
    int p = t + 1024*q, o = 9 + p;
    if(o < out_size) out[o] = best_inl[p];
  }
}

// ---------------- host ----------------
static void host_keys(uint32_t* K0h, uint32_t* K1h){
#if JAX_PARTITIONABLE
  for(int i=0;i<10;i++){ uint32_t a,b; tf2x32(0u,42u,0u,(uint32_t)i,a,b); K0h[i]=a; K1h[i]=b; }
#else
  uint32_t arr[20];
  for(int j=0;j<10;j++){ uint32_t a,b; tf2x32(0u,42u,(uint32_t)j,(uint32_t)(j+10),a,b); arr[j]=a; arr[j+10]=b; }
  for(int i=0;i<10;i++){ K0h[i]=arr[2*i]; K1h[i]=arr[2*i+1]; }
#endif
}

extern "C" void kernel_launch(void* const* d_in, const int* in_sizes, int n_in,
                              void* d_out, int out_size, void* d_ws, size_t ws_size,
                              hipStream_t stream) {
  const float* kp1 = (const float*)d_in[0];
  const float* kp2 = (const float*)d_in[1];
  float* out = (float*)d_out;
  float* ws  = (float*)d_ws;

  // ws layout (floats)
  float* stateF   = ws + 0;      // 16: [0]=best_score [1]=done [2..10]=best_model
  float* nrm      = ws + 16;     // 8
  float* best_inl = ws + 32;     // 4096
  float* p1n      = ws + 4128;   // 8192
  float* p2n      = ws + 12320;  // 8192
  float* scores   = ws + 20512;  // 1024
  float* flags    = ws + 21536;  // 1024
  float* models   = ws + 22560;  // 9216
  int*   idxs     = (int*)(ws + 31776); // 4096 ints

  uint32_t K0h[10], K1h[10];
  host_keys(K0h, K1h);

  k_init<<<1, 1024, 0, stream>>>(kp1, kp2, stateF, nrm, best_inl, p1n, p2n);
  for(int i=0;i<NIT;i++){
    k_sample<<<NBATCH, 256, 0, stream>>>(stateF, K0h[i], K1h[i], idxs);
    k_models<<<NBATCH/256, 256, 0, stream>>>(stateF, idxs, kp1, kp2, models, flags);
    k_score <<<NBATCH, 256, 0, stream>>>(stateF, models, flags, kp1, kp2, scores);
    k_polish<<<1, 512, 0, stream>>>(stateF, nrm, scores, models, kp1, kp2, p1n, p2n, best_inl, i);
  }
  k_out<<<1, 1024, 0, stream>>>(stateF, best_inl, out, out_size);
}

// Round 3
// 177.586 us; speedup vs baseline: 2.8881x; 1.4565x over previous
//
#include <hip/hip_runtime.h>
#include <cstdint>

#define JAX_PARTITIONABLE 1

#define NPTS   4096
#define NBATCH 1024
#define NIT    10

// ---------------- threefry2x32 (exact JAX rounds) ----------------
__host__ __device__ inline uint32_t rotl32(uint32_t v, uint32_t r){ return (v<<r)|(v>>(32u-r)); }

__host__ __device__ inline void tf2x32(uint32_t k0,uint32_t k1,uint32_t x0,uint32_t x1,
                                       uint32_t&o0,uint32_t&o1){
  uint32_t ks2 = k0 ^ k1 ^ 0x1BD11BDAu;
  x0 += k0; x1 += k1;
  x0+=x1; x1=rotl32(x1,13); x1^=x0;
  x0+=x1; x1=rotl32(x1,15); x1^=x0;
  x0+=x1; x1=rotl32(x1,26); x1^=x0;
  x0+=x1; x1=rotl32(x1, 6); x1^=x0;
  x0+=k1; x1+=ks2+1u;
  x0+=x1; x1=rotl32(x1,17); x1^=x0;
  x0+=x1; x1=rotl32(x1,29); x1^=x0;
  x0+=x1; x1=rotl32(x1,16); x1^=x0;
  x0+=x1; x1=rotl32(x1,24); x1^=x0;
  x0+=ks2; x1+=k0+2u;
  x0+=x1; x1=rotl32(x1,13); x1^=x0;
  x0+=x1; x1=rotl32(x1,15); x1^=x0;
  x0+=x1; x1=rotl32(x1,26); x1^=x0;
  x0+=x1; x1=rotl32(x1, 6); x1^=x0;
  x0+=k0; x1+=k1+3u;
  x0+=x1; x1=rotl32(x1,17); x1^=x0;
  x0+=x1; x1=rotl32(x1,29); x1^=x0;
  x0+=x1; x1=rotl32(x1,16); x1^=x0;
  x0+=x1; x1=rotl32(x1,24); x1^=x0;
  x0+=k1; x1+=ks2+4u;
  x0+=x1; x1=rotl32(x1,13); x1^=x0;
  x0+=x1; x1=rotl32(x1,15); x1^=x0;
  x0+=x1; x1=rotl32(x1,26); x1^=x0;
  x0+=x1; x1=rotl32(x1, 6); x1^=x0;
  x0+=ks2; x1+=k0+5u;
  o0=x0; o1=x1;
}

// ---------------- small helpers ----------------
__device__ inline float errsq_f(const float H[9], float x, float y, float kx, float ky){
  float z  = H[6]*x + H[7]*y + H[8];
  float zi = (fabsf(z) > 1e-8f) ? (1.0f/z) : 1.0f;
  float px = (H[0]*x + H[1]*y + H[2])*zi;
  float py = (H[3]*x + H[4]*y + H[5])*zi;
  float dx = px - kx, dy = py - ky;
  return dx*dx + dy*dy;
}

// H = inv(T2) * Hn * T1, then / (H22 + 1e-8). h is the 9-vector (unit-ish scale).
__device__ inline void denorm_h(const double h[9], double s1, double m1x, double m1y,
                                double s2, double m2x, double m2y, float out[9]){
  double G[3][3];
  #pragma unroll
  for(int r=0;r<3;r++){
    double h0=h[3*r], h1=h[3*r+1], h2=h[3*r+2];
    G[r][0] = h0*s1;
    G[r][1] = h1*s1;
    G[r][2] = -s1*m1x*h0 - s1*m1y*h1 + h2;
  }
  double Hm[3][3];
  double inv2 = 1.0/s2;
  #pragma unroll
  for(int c=0;c<3;c++){
    Hm[0][c] = G[0][c]*inv2 + m2x*G[2][c];
    Hm[1][c] = G[1][c]*inv2 + m2y*G[2][c];
    Hm[2][c] = G[2][c];
  }
  double invd = 1.0/(Hm[2][2] + 1e-8);
  #pragma unroll
  for(int r=0;r<3;r++)
    #pragma unroll
    for(int c=0;c<3;c++)
      out[3*r+c] = (float)(Hm[r][c]*invd);
}

// det of 3 homogeneous columns (x,y,1)
__device__ inline double det3c(double ax,double ay, double bx,double by, double cx,double cy){
  return ax*(by-cy) - bx*(ay-cy) + cx*(ay-by);
}

// projective-basis map: M sends e0,e1,e2,e0+e1+e2 -> the 4 points (any scale)
__device__ inline void h4pt(const double P[4][2], double M[3][3]){
  double c0 = det3c(P[3][0],P[3][1], P[1][0],P[1][1], P[2][0],P[2][1]);
  double c1 = det3c(P[0][0],P[0][1], P[3][0],P[3][1], P[2][0],P[2][1]);
  double c2 = det3c(P[0][0],P[0][1], P[1][0],P[1][1], P[3][0],P[3][1]);
  M[0][0]=c0*P[0][0]; M[0][1]=c1*P[1][0]; M[0][2]=c2*P[2][0];
  M[1][0]=c0*P[0][1]; M[1][1]=c1*P[1][1]; M[1][2]=c2*P[2][1];
  M[2][0]=c0;         M[2][1]=c1;         M[2][2]=c2;
}

__device__ inline void adj3(const double M[3][3], double A[3][3]){
  A[0][0]=M[1][1]*M[2][2]-M[1][2]*M[2][1];
  A[0][1]=M[0][2]*M[2][1]-M[0][1]*M[2][2];
  A[0][2]=M[0][1]*M[1][2]-M[0][2]*M[1][1];
  A[1][0]=M[1][2]*M[2][0]-M[1][0]*M[2][2];
  A[1][1]=M[0][0]*M[2][2]-M[0][2]*M[2][0];
  A[1][2]=M[0][2]*M[1][0]-M[0][0]*M[1][2];
  A[2][0]=M[1][0]*M[2][1]-M[1][1]*M[2][0];
  A[2][1]=M[0][1]*M[2][0]-M[0][0]*M[2][1];
  A[2][2]=M[0][0]*M[1][1]-M[0][1]*M[1][0];
}

// 3x3 Cholesky with clamped pivots + reciprocals
__device__ inline void chol3(const double A[3][3], double L[3][3], double r[3]){
  double d0 = A[0][0]; if(d0<1e-280) d0=1e-280;
  double l00 = sqrt(d0); double q0 = 1.0/l00;
  double l10 = A[1][0]*q0, l20 = A[2][0]*q0;
  double d1 = A[1][1]-l10*l10; if(d1<1e-280) d1=1e-280;
  double l11 = sqrt(d1); double q1=1.0/l11;
  double l21 = (A[2][1]-l20*l10)*q1;
  double d2 = A[2][2]-l20*l20-l21*l21; if(d2<1e-280) d2=1e-280;
  double l22 = sqrt(d2); double q2=1.0/l22;
  L[0][0]=l00; L[1][0]=l10; L[1][1]=l11; L[2][0]=l20; L[2][1]=l21; L[2][2]=l22;
  r[0]=q0; r[1]=q1; r[2]=q2;
}
__device__ inline void csolve3(const double L[3][3], const double r[3],
                               const double b[3], double x[3]){
  double y0=b[0]*r[0];
  double y1=(b[1]-L[1][0]*y0)*r[1];
  double y2=(b[2]-L[2][0]*y0-L[2][1]*y1)*r[2];
  x[2]=y2*r[2];
  x[1]=(y1-L[2][1]*x[2])*r[1];
  x[0]=(y0-L[1][0]*x[1]-L[2][0]*x[2])*r[0];
}

// ---------------- K0: init + full-set normalization ----------------
__global__ __launch_bounds__(1024) void k_init(const float* __restrict__ kp1,
                                               const float* __restrict__ kp2,
                                               float* stateF, float* nrm,
                                               float* best_inl, float* p1n, float* p2n){
  __shared__ double red[1024];
  const int t = threadIdx.x;
  auto blk_reduce = [&](double v)->double{
    red[t]=v; __syncthreads();
    for(int off=512; off>=1; off>>=1){ if(t<off) red[t]+=red[t+off]; __syncthreads(); }
    double rr = red[0]; __syncthreads(); return rr;
  };
  double sx1=0, sy1=0, sx2=0, sy2=0;
  #pragma unroll
  for(int q=0;q<4;q++){
    int p = t + 1024*q;
    sx1 += (double)kp1[2*p];   sy1 += (double)kp1[2*p+1];
    sx2 += (double)kp2[2*p];   sy2 += (double)kp2[2*p+1];
  }
  double m1x = blk_reduce(sx1)/(double)NPTS;
  double m1y = blk_reduce(sy1)/(double)NPTS;
  double m2x = blk_reduce(sx2)/(double)NPTS;
  double m2y = blk_reduce(sy2)/(double)NPTS;
  double a1=0, a2=0;
  #pragma unroll
  for(int q=0;q<4;q++){
    int p = t + 1024*q;
    double dx1=(double)kp1[2*p]-m1x, dy1=(double)kp1[2*p+1]-m1y;
    double dx2=(double)kp2[2*p]-m2x, dy2=(double)kp2[2*p+1]-m2y;
    a1 += sqrt(dx1*dx1+dy1*dy1);
    a2 += sqrt(dx2*dx2+dy2*dy2);
  }
  double sc1 = blk_reduce(a1)/(double)NPTS;
  double sc2 = blk_reduce(a2)/(double)NPTS;
  double s1 = 1.4142135623730951/(sc1+1e-8);
  double s2 = 1.4142135623730951/(sc2+1e-8);
  if(t==0){
    nrm[0]=(float)s1; nrm[1]=(float)m1x; nrm[2]=(float)m1y;
    nrm[3]=(float)s2; nrm[4]=(float)m2x; nrm[5]=(float)m2y;
    stateF[0]=4.0f;   // best_score init = SAMPLE
    stateF[1]=0.0f;   // done
    for(int j=0;j<9;j++) stateF[2+j]=0.0f;
  }
  #pragma unroll
  for(int q=0;q<4;q++){
    int p = t + 1024*q;
    p1n[2*p]   = (float)(s1*((double)kp1[2*p]  -m1x));
    p1n[2*p+1] = (float)(s1*((double)kp1[2*p+1]-m1y));
    p2n[2*p]   = (float)(s2*((double)kp2[2*p]  -m2x));
    p2n[2*p+1] = (float)(s2*((double)kp2[2*p+1]-m2y));
    best_inl[p] = 0.0f;
  }
}

// ---------------- K1: fused sampling (top_k 4) + analytic 4-pt model ----------------
__device__ inline void ins4(uint64_t b[4], uint64_t k){
  if(k > b[0]){ b[3]=b[2]; b[2]=b[1]; b[1]=b[0]; b[0]=k; }
  else if(k > b[1]){ b[3]=b[2]; b[2]=b[1]; b[1]=k; }
  else if(k > b[2]){ b[3]=b[2]; b[2]=k; }
  else if(k > b[3]){ b[3]=k; }
}

__global__ __launch_bounds__(256) void k_sample_models(const float* stateF,
                                                uint32_t key0, uint32_t key1,
                                                const float* __restrict__ kp1,
                                                const float* __restrict__ kp2,
                                                float* __restrict__ models,
                                                float* __restrict__ flags){
  if(stateF[1] != 0.0f) return;
  const int r = blockIdx.x;
  const int t = threadIdx.x;
  __shared__ uint64_t ls[256][4];
  uint64_t b[4] = {0ull,0ull,0ull,0ull};
  #pragma unroll
  for(int j=0;j<16;j++){
    int c = t*16 + j;
    uint32_t f = (uint32_t)(r*NPTS + c);
    uint32_t a0,a1; uint32_t bits;
#if JAX_PARTITIONABLE
    tf2x32(key0,key1, 0u, f, a0,a1);
    bits = a0 ^ a1;
#else
    const uint32_t HALF = (uint32_t)(NBATCH*NPTS/2);
    if(f < HALF){ tf2x32(key0,key1, f, f+HALF, a0,a1); bits = a0; }
    else        { tf2x32(key0,key1, f-HALF, f, a0,a1); bits = a1; }
#endif
    uint64_t v = (uint64_t)((bits>>9) + 1u);
    uint64_t key = (v<<12) | (uint64_t)(4095 - c);
    ins4(b, key);
  }
  ls[t][0]=b[0]; ls[t][1]=b[1]; ls[t][2]=b[2]; ls[t][3]=b[3];
  __syncthreads();
  for(int off=128; off>=1; off>>=1){
    if(t < off){
      uint64_t o0=ls[t+off][0], o1=ls[t+off][1], o2=ls[t+off][2], o3=ls[t+off][3];
      ins4(b,o0); ins4(b,o1); ins4(b,o2); ins4(b,o3);
      ls[t][0]=b[0]; ls[t][1]=b[1]; ls[t][2]=b[2]; ls[t][3]=b[3];
    }
    __syncthreads();
  }
  if(t==0){
    double P1[4][2], P2[4][2];
    #pragma unroll
    for(int k=0;k<4;k++){
      int id = 4095 - (int)(b[k] & 0xFFFull);
      P1[k][0]=(double)kp1[2*id]; P1[k][1]=(double)kp1[2*id+1];
      P2[k][0]=(double)kp2[2*id]; P2[k][1]=(double)kp2[2*id+1];
    }
    // validity: det-sign agreement over 4 triplets
    const int TRI[4][3] = {{0,1,2},{0,1,3},{0,2,3},{1,2,3}};
    bool valid = true;
    #pragma unroll
    for(int tq=0;tq<4;tq++){
      const int i0=TRI[tq][0], i1=TRI[tq][1], i2=TRI[tq][2];
      double d1 = det3c(P1[i0][0],P1[i0][1], P1[i1][0],P1[i1][1], P1[i2][0],P1[i2][1]);
      double d2 = det3c(P2[i0][0],P2[i0][1], P2[i1][0],P2[i1][1], P2[i2][0],P2[i2][1]);
      int s1 = (d1>0.0)-(d1<0.0), s2 = (d2>0.0)-(d2<0.0);
      if(s1 != s2) valid = false;
    }
    // analytic homography: H = MB * adj(MA)
    double MA[3][3], MB[3][3], AJ[3][3], H[3][3];
    h4pt(P1, MA); h4pt(P2, MB);
    adj3(MA, AJ);
    #pragma unroll
    for(int i=0;i<3;i++)
      #pragma unroll
      for(int j=0;j<3;j++)
        H[i][j] = MB[i][0]*AJ[0][j] + MB[i][1]*AJ[1][j] + MB[i][2]*AJ[2][j];
    // unit Frobenius norm (parity with unit eigenvector), then /(H22+1e-8)
    double n2=0.0;
    #pragma unroll
    for(int i=0;i<3;i++)
      #pragma unroll
      for(int j=0;j<3;j++) n2 += H[i][j]*H[i][j];
    double invn = 1.0/sqrt(n2);
    double invd = 1.0/(H[2][2]*invn + 1e-8);
    float Hf[9];
    #pragma unroll
    for(int i=0;i<3;i++)
      #pragma unroll
      for(int j=0;j<3;j++) Hf[3*i+j] = (float)(H[i][j]*invn*invd);
    bool diag_ok = (fminf(fminf(fabsf(Hf[0]),fabsf(Hf[4])),fabsf(Hf[8])) > 1e-4f);
    #pragma unroll
    for(int j=0;j<9;j++) models[r*9+j]=Hf[j];
    flags[r] = (valid && diag_ok) ? 1.0f : 0.0f;
  }
}

// ---------------- K3: verify (scores) ----------------
__global__ __launch_bounds__(256) void k_score(const float* stateF,
                                               const float* __restrict__ models,
                                               const float* __restrict__ flags,
                                               const float* __restrict__ kp1,
                                               const float* __restrict__ kp2,
                                               float* __restrict__ scores){
  if(stateF[1] != 0.0f) return;
  const int b = blockIdx.x;
  const int t = threadIdx.x;
  __shared__ int red[256];
  float H[9];
  #pragma unroll
  for(int j=0;j<9;j++) H[j]=models[b*9+j];
  int cnt=0;
  for(int p=t; p<NPTS; p+=256){
    float e = errsq_f(H, kp1[2*p], kp1[2*p+1], kp2[2*p], kp2[2*p+1]);
    cnt += (e <= 2.0f) ? 1 : 0;
  }
  red[t]=cnt; __syncthreads();
  for(int off=128; off>=1; off>>=1){ if(t<off) red[t]+=red[t+off]; __syncthreads(); }
  if(t==0) scores[b] = (flags[b]!=0.0f) ? (float)red[0] : -1.0f;
}

// ---------------- K5: argmax + polish + state update ----------------
// AtWA block structure: M = [[S0,0,-S1],[0,S0,-S2],[-S1,-S2,S3]] (3x3 sym blocks)
// S0=sum w*U, S1=sum w*x2*U, S2=sum w*y2*U, S3=sum w*(x2^2+y2^2)*U,
// U = packed sym moment [x1^2, x1y1, y1^2, x1, y1, 1] of u=(x1,y1,1).
// Solve M v = u via S0-Cholesky + 3x3 Schur complement.
__global__ __launch_bounds__(512) void k_polish(float* stateF, const float* nrm,
                                                const float* __restrict__ scores,
                                                const float* __restrict__ models,
                                                const float* __restrict__ kp1,
                                                const float* __restrict__ kp2,
                                                const float* __restrict__ p1n,
                                                const float* __restrict__ p2n,
                                                float* __restrict__ best_inl,
                                                int iter){
  if(stateF[1] != 0.0f) return;
  const int t = threadIdx.x;
  __shared__ uint64_t red[512];
  __shared__ float partials[8][24];
  __shared__ float sM[24];
  __shared__ float sModel[9];
  __shared__ float curH[9];
  __shared__ unsigned char inlb[2][NPTS];

  // ---- argmax over 1024 scores (first-index tie-break) ----
  {
    float sA = scores[t], sB = scores[t+512];
    uint64_t kA = ((uint64_t)(uint32_t)(int)(sA + 2.0f) << 12) | (uint64_t)(1023 - t);
    uint64_t kB = ((uint64_t)(uint32_t)(int)(sB + 2.0f) << 12) | (uint64_t)(1023 - (t+512));
    red[t] = (kA >= kB) ? kA : kB;
  }
  __syncthreads();
  for(int off=256; off>=1; off>>=1){
    if(t<off){ uint64_t o=red[t+off]; if(o>red[t]) red[t]=o; }
    __syncthreads();
  }
  const int bi = 1023 - (int)(red[0] & 0xFFFull);
  const float selScore = (float)((int)(red[0] >> 12)) - 2.0f;
  __syncthreads();

  const float bestScore = stateF[0];
  const bool improve = (selScore > bestScore);
  if(!improve) return;

  if(t<9) sModel[t] = models[bi*9+t];
  __syncthreads();

  // cache this thread's 8 points
  float U1[8],V1[8],U2[8],V2[8],X1[8],Y1[8],X2[8],Y2[8];
  #pragma unroll
  for(int q=0;q<8;q++){
    int p = t + 512*q;
    U1[q]=kp1[2*p]; V1[q]=kp1[2*p+1];
    U2[q]=kp2[2*p]; V2[q]=kp2[2*p+1];
    X1[q]=p1n[2*p]; Y1[q]=p1n[2*p+1];
    X2[q]=p2n[2*p]; Y2[q]=p2n[2*p+1];
  }
  // initial inliers of selected model
  {
    float H[9];
    #pragma unroll
    for(int j=0;j<9;j++) H[j]=sModel[j];
    #pragma unroll
    for(int q=0;q<8;q++){
      int p = t + 512*q;
      float e = errsq_f(H, U1[q],V1[q],U2[q],V2[q]);
      inlb[0][p] = (e <= 2.0f) ? 1 : 0;
    }
  }
  __syncthreads();

  int cur = 0;
  float score = selScore;
  bool active = true;
  float wreg[8];

  const double ns1=(double)nrm[0], nm1x=(double)nrm[1], nm1y=(double)nrm[2];
  const double ns2=(double)nrm[3], nm2x=(double)nrm[4], nm2y=(double)nrm[5];

  auto DLT = [&](){
    float part[24];
    #pragma unroll
    for(int k=0;k<24;k++) part[k]=0.0f;
    #pragma unroll
    for(int q=0;q<8;q++){
      float w = wreg[q];
      float x=X1[q], y=Y1[q], x2=X2[q], y2=Y2[q];
      float wx = w*x, wy = w*y;
      float m0=wx*x, m1=wx*y, m2=wy*y, m3=wx, m4=wy, m5=w;
      float s3 = x2*x2 + y2*y2;
      part[0]+=m0; part[1]+=m1; part[2]+=m2; part[3]+=m3; part[4]+=m4; part[5]+=m5;
      part[6]+=x2*m0; part[7]+=x2*m1; part[8]+=x2*m2; part[9]+=x2*m3; part[10]+=x2*m4; part[11]+=x2*m5;
      part[12]+=y2*m0; part[13]+=y2*m1; part[14]+=y2*m2; part[15]+=y2*m3; part[16]+=y2*m4; part[17]+=y2*m5;
      part[18]+=s3*m0; part[19]+=s3*m1; part[20]+=s3*m2; part[21]+=s3*m3; part[22]+=s3*m4; part[23]+=s3*m5;
    }
    #pragma unroll
    for(int off=32; off>=1; off>>=1){
      #pragma unroll
      for(int k=0;k<24;k++) part[k] += __shfl_down(part[k], off, 64);
    }
    const int wv = t>>6, lane = t&63;
    if(lane==0){
      #pragma unroll
      for(int k=0;k<24;k++) partials[wv][k]=part[k];
    }
    __syncthreads();
    if(t<24){
      float acc=0.0f;
      #pragma unroll
      for(int w8=0; w8<8; w8++) acc += partials[w8][t];
      sM[t]=acc;
    }
    __syncthreads();
    if(t==0){
      // unpack 3x3 sym blocks (f64)
      double A0[3][3],A1[3][3],A2[3][3],A3[3][3];
      auto unpack=[&](const float* s, double M[3][3]){
        M[0][0]=(double)s[0]; M[0][1]=(double)s[1]; M[0][2]=(double)s[3];
        M[1][0]=(double)s[1]; M[1][1]=(double)s[2]; M[1][2]=(double)s[4];
        M[2][0]=(double)s[3]; M[2][1]=(double)s[4]; M[2][2]=(double)s[5];
      };
      unpack(sM+0,A0); unpack(sM+6,A1); unpack(sM+12,A2); unpack(sM+18,A3);

      double L0[3][3], q0[3];
      chol3(A0, L0, q0);
      // T1 = S0^-1 S1, T2 = S0^-1 S2
      double T1[3][3], T2[3][3];
      #pragma unroll
      for(int c=0;c<3;c++){
        double col[3]={A1[0][c],A1[1][c],A1[2][c]}, x[3];
        csolve3(L0,q0,col,x);
        T1[0][c]=x[0]; T1[1][c]=x[1]; T1[2][c]=x[2];
      }
      #pragma unroll
      for(int c=0;c<3;c++){
        double col[3]={A2[0][c],A2[1][c],A2[2][c]}, x[3];
        csolve3(L0,q0,col,x);
        T2[0][c]=x[0]; T2[1][c]=x[1]; T2[2][c]=x[2];
      }
      // Schur = S3 - S1*T1 - S2*T2
      double Sc[3][3];
      #pragma unroll
      for(int i=0;i<3;i++)
        #pragma unroll
        for(int j=0;j<3;j++){
          double s = A3[i][j];
          #pragma unroll
          for(int k=0;k<3;k++) s -= A1[i][k]*T1[k][j] + A2[i][k]*T2[k][j];
          Sc[i][j]=s;
        }
      double Ls[3][3], qs[3];
      chol3(Sc, Ls, qs);

      // 2 inverse iterations: solve M v_new = v
      double v[9];
      #pragma unroll
      for(int i=0;i<9;i++) v[i]=1.0;
      #pragma unroll
      for(int itn=0; itn<2; itn++){
        double a[3]={v[0],v[1],v[2]}, bb[3]={v[3],v[4],v[5]}, cc[3]={v[6],v[7],v[8]};
        double w1[3],w2[3];
        csolve3(L0,q0,a,w1); csolve3(L0,q0,bb,w2);
        double rhs[3];
        #pragma unroll
        for(int j=0;j<3;j++)
          rhs[j] = cc[j] + T1[0][j]*a[0]+T1[1][j]*a[1]+T1[2][j]*a[2]
                         + T2[0][j]*bb[0]+T2[1][j]*bb[1]+T2[2][j]*bb[2];
        double rr[3];
        csolve3(Ls,qs,rhs,rr);
        #pragma unroll
        for(int i=0;i<3;i++){
          v[i]   = w1[i] + T1[i][0]*rr[0]+T1[i][1]*rr[1]+T1[i][2]*rr[2];
          v[3+i] = w2[i] + T2[i][0]*rr[0]+T2[i][1]*rr[1]+T2[i][2]*rr[2];
          v[6+i] = rr[i];
        }
        if(itn==0){
          double mx=0.0;
          #pragma unroll
          for(int i=0;i<9;i++){ double aa=fabs(v[i]); if(aa>mx) mx=aa; }
          double sc = 1.0/(mx + 1e-300);
          #pragma unroll
          for(int i=0;i<9;i++) v[i]*=sc;
        }
      }
      double n2=0.0;
      #pragma unroll
      for(int i=0;i<9;i++) n2 += v[i]*v[i];
      double invn = 1.0/sqrt(n2);
      #pragma unroll
      for(int i=0;i<9;i++) v[i]*=invn;
      denorm_h(v, ns1,nm1x,nm1y, ns2,nm2x,nm2y, curH);
    }
    __syncthreads();
  };

  for(int lo=0; lo<5; lo++){
    // iterated DLT: first with 0/1 weights
    #pragma unroll
    for(int q=0;q<8;q++){ int p=t+512*q; wreg[q] = inlb[cur][p] ? 1.0f : 0.0f; }
    DLT();
    for(int itp=0; itp<4; itp++){
      float H[9];
      #pragma unroll
      for(int j=0;j<9;j++) H[j]=curH[j];
      #pragma unroll
      for(int q=0;q<8;q++){
        int p=t+512*q;
        float e   = errsq_f(H, U1[q],V1[q],U2[q],V2[q]);
        float err = sqrtf(e + 1e-8f);
        wreg[q] = inlb[cur][p] ? expf(-err/18.0f) : 0.0f;
      }
      DLT();
    }
    // verify polished model
    float scoreLo;
    {
      float H[9];
      #pragma unroll
      for(int j=0;j<9;j++) H[j]=curH[j];
      int c=0;
      #pragma unroll
      for(int q=0;q<8;q++){
        int p=t+512*q;
        float e = errsq_f(H, U1[q],V1[q],U2[q],V2[q]);
        unsigned char bb = (e <= 2.0f) ? 1 : 0;
        inlb[cur^1][p] = bb;
        c += bb;
      }
      red[t]=(uint64_t)c; __syncthreads();
      for(int off=256; off>=1; off>>=1){ if(t<off) red[t]+=red[t+off]; __syncthreads(); }
      scoreLo = (float)(int)(red[0]);
      __syncthreads();
    }
    bool better = active && (scoreLo > score);
    if(better){
      if(t<9) sModel[t]=curH[t];
      cur ^= 1;
      score = scoreLo;
    }
    active = better;
    __syncthreads();
    if(!active) break;
  }

  // commit state
  if(t<9) stateF[2+t] = sModel[t];
  #pragma unroll
  for(int q=0;q<8;q++){ int p=t+512*q; best_inl[p] = inlb[cur][p] ? 1.0f : 0.0f; }
  if(t==0){
    stateF[0] = score;
    float ratio = floorf(score) / 4096.0f;
    float r2 = ratio*ratio, r4 = r2*r2;
    float q  = 1.0f - r4;
    q = fminf(fmaxf(q, 1e-12f), (float)(1.0 - 1e-12));
    float max_samp = (score >= 4096.0f) ? 1.0f : (logf(0.01f)/logf(q));
    stateF[1] = (((float)((iter+1)*NBATCH)) >= floorf(max_samp)) ? 1.0f : 0.0f;
  }
}

// ---------------- K6: writeout ----------------
__global__ __launch_bounds__(1024) void k_out(const float* stateF, const float* best_inl,
                                              float* __restrict__ out, int out_size){
  const int t = threadIdx.x;
  if(t<9 && t<out_size) out[t] = stateF[2+t];
  #pragma unroll
  for(int q=0;q<4;q++){
    int p = t + 1024*q, o = 9 + p;
    if(o < out_size) out[o] = best_inl[p];
  }
}

// ---------------- host ----------------
static void host_keys(uint32_t* K0h, uint32_t* K1h){
#if JAX_PARTITIONABLE
  for(int i=0;i<10;i++){ uint32_t a,b; tf2x32(0u,42u,0u,(uint32_t)i,a,b); K0h[i]=a; K1h[i]=b; }
#else
  uint32_t arr[20];
  for(int j=0;j<10;j++){ uint32_t a,b; tf2x32(0u,42u,(uint32_t)j,(uint32_t)(j+10),a,b); arr[j]=a; arr[j+10]=b; }
  for(int i=0;i<10;i++){ K0h[i]=arr[2*i]; K1h[i]=arr[2*i+1]; }
#endif
}

extern "C" void kernel_launch(void* const* d_in, const int* in_sizes, int n_in,
                              void* d_out, int out_size, void* d_ws, size_t ws_size,
                              hipStream_t stream) {
  const float* kp1 = (const float*)d_in[0];
  const float* kp2 = (const float*)d_in[1];
  float* out = (float*)d_out;
  float* ws  = (float*)d_ws;

  // ws layout (floats)
  float* stateF   = ws + 0;      // 16: [0]=best_score [1]=done [2..10]=best_model
  float* nrm      = ws + 16;     // 8
  float* best_inl = ws + 32;     // 4096
  float* p1n      = ws + 4128;   // 8192
  float* p2n      = ws + 12320;  // 8192
  float* scores   = ws + 20512;  // 1024
  float* flags    = ws + 21536;  // 1024
  float* models   = ws + 22560;  // 9216

  uint32_t K0h[10], K1h[10];
  host_keys(K0h, K1h);

  k_init<<<1, 1024, 0, stream>>>(kp1, kp2, stateF, nrm, best_inl, p1n, p2n);
  for(int i=0;i<NIT;i++){
    k_sample_models<<<NBATCH, 256, 0, stream>>>(stateF, K0h[i], K1h[i], kp1, kp2, models, flags);
    k_score <<<NBATCH, 256, 0, stream>>>(stateF, models, flags, kp1, kp2, scores);
    k_polish<<<1, 512, 0, stream>>>(stateF, nrm, scores, models, kp1, kp2, p1n, p2n, best_inl, i);
  }
  k_out<<<1, 1024, 0, stream>>>(stateF, best_inl, out, out_size);
}

// Round 5
// 126.353 us; speedup vs baseline: 4.0592x; 1.4055x over previous
//
#include <hip/hip_runtime.h>
#include <cstdint>

#define JAX_PARTITIONABLE 1

#define NPTS   4096
#define NBATCH 1024
#define NIT    10

// ---------------- threefry2x32 (exact JAX rounds) ----------------
__host__ __device__ inline uint32_t rotl32(uint32_t v, uint32_t r){ return (v<<r)|(v>>(32u-r)); }

__host__ __device__ inline void tf2x32(uint32_t k0,uint32_t k1,uint32_t x0,uint32_t x1,
                                       uint32_t&o0,uint32_t&o1){
  uint32_t ks2 = k0 ^ k1 ^ 0x1BD11BDAu;
  x0 += k0; x1 += k1;
  x0+=x1; x1=rotl32(x1,13); x1^=x0;
  x0+=x1; x1=rotl32(x1,15); x1^=x0;
  x0+=x1; x1=rotl32(x1,26); x1^=x0;
  x0+=x1; x1=rotl32(x1, 6); x1^=x0;
  x0+=k1; x1+=ks2+1u;
  x0+=x1; x1=rotl32(x1,17); x1^=x0;
  x0+=x1; x1=rotl32(x1,29); x1^=x0;
  x0+=x1; x1=rotl32(x1,16); x1^=x0;
  x0+=x1; x1=rotl32(x1,24); x1^=x0;
  x0+=ks2; x1+=k0+2u;
  x0+=x1; x1=rotl32(x1,13); x1^=x0;
  x0+=x1; x1=rotl32(x1,15); x1^=x0;
  x0+=x1; x1=rotl32(x1,26); x1^=x0;
  x0+=x1; x1=rotl32(x1, 6); x1^=x0;
  x0+=k0; x1+=k1+3u;
  x0+=x1; x1=rotl32(x1,17); x1^=x0;
  x0+=x1; x1=rotl32(x1,29); x1^=x0;
  x0+=x1; x1=rotl32(x1,16); x1^=x0;
  x0+=x1; x1=rotl32(x1,24); x1^=x0;
  x0+=k1; x1+=ks2+4u;
  x0+=x1; x1=rotl32(x1,13); x1^=x0;
  x0+=x1; x1=rotl32(x1,15); x1^=x0;
  x0+=x1; x1=rotl32(x1,26); x1^=x0;
  x0+=x1; x1=rotl32(x1, 6); x1^=x0;
  x0+=ks2; x1+=k0+5u;
  o0=x0; o1=x1;
}

// ---------------- small helpers ----------------
__device__ inline float errsq_f(const float H[9], float x, float y, float kx, float ky){
  float z  = H[6]*x + H[7]*y + H[8];
  float zi = (fabsf(z) > 1e-8f) ? (1.0f/z) : 1.0f;
  float px = (H[0]*x + H[1]*y + H[2])*zi;
  float py = (H[3]*x + H[4]*y + H[5])*zi;
  float dx = px - kx, dy = py - ky;
  return dx*dx + dy*dy;
}

// H = inv(T2) * Hn * T1, then / (H22 + 1e-8). h is the 9-vector (unit-ish scale).
__device__ inline void denorm_h(const double h[9], double s1, double m1x, double m1y,
                                double s2, double m2x, double m2y, float out[9]){
  double G[3][3];
  #pragma unroll
  for(int r=0;r<3;r++){
    double h0=h[3*r], h1=h[3*r+1], h2=h[3*r+2];
    G[r][0] = h0*s1;
    G[r][1] = h1*s1;
    G[r][2] = -s1*m1x*h0 - s1*m1y*h1 + h2;
  }
  double Hm[3][3];
  double inv2 = 1.0/s2;
  #pragma unroll
  for(int c=0;c<3;c++){
    Hm[0][c] = G[0][c]*inv2 + m2x*G[2][c];
    Hm[1][c] = G[1][c]*inv2 + m2y*G[2][c];
    Hm[2][c] = G[2][c];
  }
  double invd = 1.0/(Hm[2][2] + 1e-8);
  #pragma unroll
  for(int r=0;r<3;r++)
    #pragma unroll
    for(int c=0;c<3;c++)
      out[3*r+c] = (float)(Hm[r][c]*invd);
}

// det of 3 homogeneous columns (x,y,1)
__device__ inline double det3c(double ax,double ay, double bx,double by, double cx,double cy){
  return ax*(by-cy) - bx*(ay-cy) + cx*(ay-by);
}

// projective-basis map: M sends e0,e1,e2,e0+e1+e2 -> the 4 points (any scale)
__device__ inline void h4pt(const double P[4][2], double M[3][3]){
  double c0 = det3c(P[3][0],P[3][1], P[1][0],P[1][1], P[2][0],P[2][1]);
  double c1 = det3c(P[0][0],P[0][1], P[3][0],P[3][1], P[2][0],P[2][1]);
  double c2 = det3c(P[0][0],P[0][1], P[1][0],P[1][1], P[3][0],P[3][1]);
  M[0][0]=c0*P[0][0]; M[0][1]=c1*P[1][0]; M[0][2]=c2*P[2][0];
  M[1][0]=c0*P[0][1]; M[1][1]=c1*P[1][1]; M[1][2]=c2*P[2][1];
  M[2][0]=c0;         M[2][1]=c1;         M[2][2]=c2;
}

__device__ inline void adj3(const double M[3][3], double A[3][3]){
  A[0][0]=M[1][1]*M[2][2]-M[1][2]*M[2][1];
  A[0][1]=M[0][2]*M[2][1]-M[0][1]*M[2][2];
  A[0][2]=M[0][1]*M[1][2]-M[0][2]*M[1][1];
  A[1][0]=M[1][2]*M[2][0]-M[1][0]*M[2][2];
  A[1][1]=M[0][0]*M[2][2]-M[0][2]*M[2][0];
  A[1][2]=M[0][2]*M[1][0]-M[0][0]*M[1][2];
  A[2][0]=M[1][0]*M[2][1]-M[1][1]*M[2][0];
  A[2][1]=M[0][1]*M[2][0]-M[0][0]*M[2][1];
  A[2][2]=M[0][0]*M[1][1]-M[0][1]*M[1][0];
}

// 3x3 Cholesky with clamped pivots + reciprocals
__device__ inline void chol3(const double A[3][3], double L[3][3], double r[3]){
  double d0 = A[0][0]; if(d0<1e-280) d0=1e-280;
  double l00 = sqrt(d0); double q0 = 1.0/l00;
  double l10 = A[1][0]*q0, l20 = A[2][0]*q0;
  double d1 = A[1][1]-l10*l10; if(d1<1e-280) d1=1e-280;
  double l11 = sqrt(d1); double q1=1.0/l11;
  double l21 = (A[2][1]-l20*l10)*q1;
  double d2 = A[2][2]-l20*l20-l21*l21; if(d2<1e-280) d2=1e-280;
  double l22 = sqrt(d2); double q2=1.0/l22;
  L[0][0]=l00; L[1][0]=l10; L[1][1]=l11; L[2][0]=l20; L[2][1]=l21; L[2][2]=l22;
  r[0]=q0; r[1]=q1; r[2]=q2;
}
__device__ inline void csolve3(const double L[3][3], const double r[3],
                               const double b[3], double x[3]){
  double y0=b[0]*r[0];
  double y1=(b[1]-L[1][0]*y0)*r[1];
  double y2=(b[2]-L[2][0]*y0-L[2][1]*y1)*r[2];
  x[2]=y2*r[2];
  x[1]=(y1-L[2][1]*x[2])*r[1];
  x[0]=(y0-L[1][0]*x[1]-L[2][0]*x[2])*r[0];
}

// ---------------- K0: init + full-set normalization ----------------
__global__ __launch_bounds__(1024) void k_init(const float* __restrict__ kp1,
                                               const float* __restrict__ kp2,
                                               float* stateF, float* nrm,
                                               float* best_inl, float* p1n, float* p2n){
  __shared__ double red[1024];
  const int t = threadIdx.x;
  auto blk_reduce = [&](double v)->double{
    red[t]=v; __syncthreads();
    for(int off=512; off>=1; off>>=1){ if(t<off) red[t]+=red[t+off]; __syncthreads(); }
    double rr = red[0]; __syncthreads(); return rr;
  };
  double sx1=0, sy1=0, sx2=0, sy2=0;
  #pragma unroll
  for(int q=0;q<4;q++){
    int p = t + 1024*q;
    sx1 += (double)kp1[2*p];   sy1 += (double)kp1[2*p+1];
    sx2 += (double)kp2[2*p];   sy2 += (double)kp2[2*p+1];
  }
  double m1x = blk_reduce(sx1)/(double)NPTS;
  double m1y = blk_reduce(sy1)/(double)NPTS;
  double m2x = blk_reduce(sx2)/(double)NPTS;
  double m2y = blk_reduce(sy2)/(double)NPTS;
  double a1=0, a2=0;
  #pragma unroll
  for(int q=0;q<4;q++){
    int p = t + 1024*q;
    double dx1=(double)kp1[2*p]-m1x, dy1=(double)kp1[2*p+1]-m1y;
    double dx2=(double)kp2[2*p]-m2x, dy2=(double)kp2[2*p+1]-m2y;
    a1 += sqrt(dx1*dx1+dy1*dy1);
    a2 += sqrt(dx2*dx2+dy2*dy2);
  }
  double sc1 = blk_reduce(a1)/(double)NPTS;
  double sc2 = blk_reduce(a2)/(double)NPTS;
  double s1 = 1.4142135623730951/(sc1+1e-8);
  double s2 = 1.4142135623730951/(sc2+1e-8);
  if(t==0){
    nrm[0]=(float)s1; nrm[1]=(float)m1x; nrm[2]=(float)m1y;
    nrm[3]=(float)s2; nrm[4]=(float)m2x; nrm[5]=(float)m2y;
    stateF[0]=4.0f;   // best_score init = SAMPLE
    stateF[1]=0.0f;   // done
    for(int j=0;j<9;j++) stateF[2+j]=0.0f;
  }
  #pragma unroll
  for(int q=0;q<4;q++){
    int p = t + 1024*q;
    p1n[2*p]   = (float)(s1*((double)kp1[2*p]  -m1x));
    p1n[2*p+1] = (float)(s1*((double)kp1[2*p+1]-m1y));
    p2n[2*p]   = (float)(s2*((double)kp2[2*p]  -m2x));
    p2n[2*p+1] = (float)(s2*((double)kp2[2*p+1]-m2y));
    best_inl[p] = 0.0f;
  }
}

// ---------------- K1: fused sampling + analytic 4-pt model + scoring ----------------
__device__ inline void ins4(uint64_t b[4], uint64_t k){
  if(k > b[0]){ b[3]=b[2]; b[2]=b[1]; b[1]=b[0]; b[0]=k; }
  else if(k > b[1]){ b[3]=b[2]; b[2]=b[1]; b[1]=k; }
  else if(k > b[2]){ b[3]=b[2]; b[2]=k; }
  else if(k > b[3]){ b[3]=k; }
}

__global__ __launch_bounds__(256) void k_sample_score(const float* stateF,
                                                uint32_t key0, uint32_t key1,
                                                const float* __restrict__ kp1,
                                                const float* __restrict__ kp2,
                                                float* __restrict__ models,
                                                float* __restrict__ scores){
  if(stateF[1] != 0.0f) return;
  const int r = blockIdx.x;
  const int t = threadIdx.x;
  __shared__ uint64_t ls[256][4];
  __shared__ float sH[9];
  __shared__ int   sFlag;
  __shared__ int   redi[4];
  uint64_t b[4] = {0ull,0ull,0ull,0ull};
  #pragma unroll
  for(int j=0;j<16;j++){
    int c = t*16 + j;
    uint32_t f = (uint32_t)(r*NPTS + c);
    uint32_t a0,a1; uint32_t bits;
#if JAX_PARTITIONABLE
    tf2x32(key0,key1, 0u, f, a0,a1);
    bits = a0 ^ a1;
#else
    const uint32_t HALF = (uint32_t)(NBATCH*NPTS/2);
    if(f < HALF){ tf2x32(key0,key1, f, f+HALF, a0,a1); bits = a0; }
    else        { tf2x32(key0,key1, f-HALF, f, a0,a1); bits = a1; }
#endif
    uint64_t v = (uint64_t)((bits>>9) + 1u);
    uint64_t key = (v<<12) | (uint64_t)(4095 - c);
    ins4(b, key);
  }
  ls[t][0]=b[0]; ls[t][1]=b[1]; ls[t][2]=b[2]; ls[t][3]=b[3];
  __syncthreads();
  for(int off=128; off>=1; off>>=1){
    if(t < off){
      uint64_t o0=ls[t+off][0], o1=ls[t+off][1], o2=ls[t+off][2], o3=ls[t+off][3];
      ins4(b,o0); ins4(b,o1); ins4(b,o2); ins4(b,o3);
      ls[t][0]=b[0]; ls[t][1]=b[1]; ls[t][2]=b[2]; ls[t][3]=b[3];
    }
    __syncthreads();
  }
  if(t==0){
    double P1[4][2], P2[4][2];
    #pragma unroll
    for(int k=0;k<4;k++){
      int id = 4095 - (int)(b[k] & 0xFFFull);
      P1[k][0]=(double)kp1[2*id]; P1[k][1]=(double)kp1[2*id+1];
      P2[k][0]=(double)kp2[2*id]; P2[k][1]=(double)kp2[2*id+1];
    }
    // validity: det-sign agreement over 4 triplets
    const int TRI[4][3] = {{0,1,2},{0,1,3},{0,2,3},{1,2,3}};
    bool valid = true;
    #pragma unroll
    for(int tq=0;tq<4;tq++){
      const int i0=TRI[tq][0], i1=TRI[tq][1], i2=TRI[tq][2];
      double d1 = det3c(P1[i0][0],P1[i0][1], P1[i1][0],P1[i1][1], P1[i2][0],P1[i2][1]);
      double d2 = det3c(P2[i0][0],P2[i0][1], P2[i1][0],P2[i1][1], P2[i2][0],P2[i2][1]);
      int s1 = (d1>0.0)-(d1<0.0), s2 = (d2>0.0)-(d2<0.0);
      if(s1 != s2) valid = false;
    }
    // analytic homography: H = MB * adj(MA)
    double MA[3][3], MB[3][3], AJ[3][3], H[3][3];
    h4pt(P1, MA); h4pt(P2, MB);
    adj3(MA, AJ);
    #pragma unroll
    for(int i=0;i<3;i++)
      #pragma unroll
      for(int j=0;j<3;j++)
        H[i][j] = MB[i][0]*AJ[0][j] + MB[i][1]*AJ[1][j] + MB[i][2]*AJ[2][j];
    // unit Frobenius norm (parity with unit eigenvector), then /(H22+1e-8)
    double n2=0.0;
    #pragma unroll
    for(int i=0;i<3;i++)
      #pragma unroll
      for(int j=0;j<3;j++) n2 += H[i][j]*H[i][j];
    double invn = 1.0/sqrt(n2);
    double invd = 1.0/(H[2][2]*invn + 1e-8);
    float Hf[9];
    #pragma unroll
    for(int i=0;i<3;i++)
      #pragma unroll
      for(int j=0;j<3;j++) Hf[3*i+j] = (float)(H[i][j]*invn*invd);
    bool diag_ok = (fminf(fminf(fabsf(Hf[0]),fabsf(Hf[4])),fabsf(Hf[8])) > 1e-4f);
    #pragma unroll
    for(int j=0;j<9;j++){ models[r*9+j]=Hf[j]; sH[j]=Hf[j]; }
    sFlag = (valid && diag_ok) ? 1 : 0;
  }
  __syncthreads();
  // ---- score this block's model over all 4096 points ----
  float H[9];
  #pragma unroll
  for(int j=0;j<9;j++) H[j]=sH[j];
  int cnt=0;
  #pragma unroll
  for(int j=0;j<16;j++){
    int p = t + 256*j;
    float e = errsq_f(H, kp1[2*p], kp1[2*p+1], kp2[2*p], kp2[2*p+1]);
    cnt += (e <= 2.0f) ? 1 : 0;
  }
  #pragma unroll
  for(int off=32; off>=1; off>>=1) cnt += __shfl_down(cnt, off, 64);
  if((t&63)==0) redi[t>>6]=cnt;
  __syncthreads();
  if(t==0) scores[r] = sFlag ? (float)(redi[0]+redi[1]+redi[2]+redi[3]) : -1.0f;
}

// ---------------- K5: argmax + polish + state update ----------------
// AtWA block structure: M = [[S0,0,-S1],[0,S0,-S2],[-S1,-S2,S3]] (3x3 sym blocks)
// S0=sum w*U, S1=sum w*x2*U, S2=sum w*y2*U, S3=sum w*(x2^2+y2^2)*U,
// U = packed sym moment [x1^2, x1y1, y1^2, x1, y1, 1] of u=(x1,y1,1).
// Solve M v = u via S0-Cholesky + 3x3 Schur complement.
// Reduction: LDS-transpose (b128 store/load) instead of shuffle butterfly —
// the butterfly's 144 bpermutes/lane serialized on the per-CU LDS pipe.
__global__ __launch_bounds__(512) void k_polish(float* stateF, const float* nrm,
                                                const float* __restrict__ scores,
                                                const float* __restrict__ models,
                                                const float* __restrict__ kp1,
                                                const float* __restrict__ kp2,
                                                const float* __restrict__ p1n,
                                                const float* __restrict__ p2n,
                                                float* __restrict__ best_inl,
                                                int iter){
  if(stateF[1] != 0.0f) return;
  const int t = threadIdx.x;
  const int lane = t & 63, wv = t >> 6;
  __shared__ float  p2b[512][28];     // 56 KB: per-thread 24 partials (+pad, 16B-aligned rows)
  __shared__ double p3[16][25];       // stage-A output
  __shared__ double sMd[24];
  __shared__ uint64_t redu[8];
  __shared__ int   redi[8];
  __shared__ float sScore;
  __shared__ float sModel[9];
  __shared__ float curHn[9];          // normalized-frame H (unit 9-vec)
  __shared__ float curH[9];           // original-frame H (denormalized)
  __shared__ unsigned char inlb[2][NPTS];

  // ---- argmax over 1024 scores (first-index tie-break) ----
  {
    float sA = scores[t], sB = scores[t+512];
    uint64_t kA = ((uint64_t)(uint32_t)(int)(sA + 2.0f) << 12) | (uint64_t)(1023 - t);
    uint64_t kB = ((uint64_t)(uint32_t)(int)(sB + 2.0f) << 12) | (uint64_t)(1023 - (t+512));
    uint64_t k = (kA >= kB) ? kA : kB;
    #pragma unroll
    for(int off=32; off>=1; off>>=1){
      uint64_t o = __shfl_down(k, off, 64);
      if(o > k) k = o;
    }
    if(lane==0) redu[wv]=k;
  }
  __syncthreads();
  if(t==0){
    uint64_t m=redu[0];
    #pragma unroll
    for(int w8=1;w8<8;w8++) if(redu[w8]>m) m=redu[w8];
    redu[0]=m;
  }
  __syncthreads();
  const int bi = 1023 - (int)(redu[0] & 0xFFFull);
  const float selScore = (float)((int)(redu[0] >> 12)) - 2.0f;

  const float bestScore = stateF[0];
  const bool improve = (selScore > bestScore);
  if(!improve) return;

  if(t<9) sModel[t] = models[bi*9+t];
  __syncthreads();

  // cache this thread's 8 points (orig + normalized)
  float U1[8],V1[8],U2[8],V2[8],X1[8],Y1[8],X2[8],Y2[8];
  #pragma unroll
  for(int q=0;q<8;q++){
    int p = t + 512*q;
    U1[q]=kp1[2*p]; V1[q]=kp1[2*p+1];
    U2[q]=kp2[2*p]; V2[q]=kp2[2*p+1];
    X1[q]=p1n[2*p]; Y1[q]=p1n[2*p+1];
    X2[q]=p2n[2*p]; Y2[q]=p2n[2*p+1];
  }
  // initial inliers of selected model (orig frame — matches verify())
  {
    float H[9];
    #pragma unroll
    for(int j=0;j<9;j++) H[j]=sModel[j];
    #pragma unroll
    for(int q=0;q<8;q++){
      int p = t + 512*q;
      float e = errsq_f(H, U1[q],V1[q],U2[q],V2[q]);
      inlb[0][p] = (e <= 2.0f) ? 1 : 0;
    }
  }
  __syncthreads();

  int cur = 0;
  float score = selScore;
  bool active = true;
  float wreg[8];

  const double ns1=(double)nrm[0], nm1x=(double)nrm[1], nm1y=(double)nrm[2];
  const double ns2=(double)nrm[3], nm2x=(double)nrm[4], nm2y=(double)nrm[5];
  const float s2f  = nrm[3];
  const float epsn = 1e-8f*s2f*s2f;            // err_orig = sqrt(e_n + eps*s2^2)/s2
  const float wk   = 1.0f/(18.0f*s2f);         // exp(-err_orig/18)

  auto DLT = [&](bool denorm_now){
    float part[24];
    #pragma unroll
    for(int k=0;k<24;k++) part[k]=0.0f;
    #pragma unroll
    for(int q=0;q<8;q++){
      float w = wreg[q];
      float x=X1[q], y=Y1[q], x2=X2[q], y2=Y2[q];
      float wx = w*x, wy = w*y;
      float m0=wx*x, m1=wx*y, m2=wy*y;
      float s3 = x2*x2 + y2*y2;
      part[0]+=m0; part[1]+=m1; part[2]+=m2; part[3]+=wx; part[4]+=wy; part[5]+=w;
      part[6]+=x2*m0; part[7]+=x2*m1; part[8]+=x2*m2; part[9]+=x2*wx; part[10]+=x2*wy; part[11]+=x2*w;
      part[12]+=y2*m0; part[13]+=y2*m1; part[14]+=y2*m2; part[15]+=y2*wx; part[16]+=y2*wy; part[17]+=y2*w;
      part[18]+=s3*m0; part[19]+=s3*m1; part[20]+=s3*m2; part[21]+=s3*wx; part[22]+=s3*wy; part[23]+=s3*w;
    }
    // store 24 partials as 6 x float4
    float4* rowp = reinterpret_cast<float4*>(&p2b[t][0]);
    rowp[0]=make_float4(part[0],part[1],part[2],part[3]);
    rowp[1]=make_float4(part[4],part[5],part[6],part[7]);
    rowp[2]=make_float4(part[8],part[9],part[10],part[11]);
    rowp[3]=make_float4(part[12],part[13],part[14],part[15]);
    rowp[4]=make_float4(part[16],part[17],part[18],part[19]);
    rowp[5]=make_float4(part[20],part[21],part[22],part[23]);
    __syncthreads();
    // stage A: 96 threads, each sums 32 rows of one float4 column (f64 accum)
    if(t<96){
      int qd = t%6, seg = t/6;
      double a0=0,a1=0,a2=0,a3=0;
      #pragma unroll
      for(int i=0;i<32;i++){
        float4 v = *reinterpret_cast<const float4*>(&p2b[seg*32+i][qd*4]);
        a0+=(double)v.x; a1+=(double)v.y; a2+=(double)v.z; a3+=(double)v.w;
      }
      p3[seg][qd*4+0]=a0; p3[seg][qd*4+1]=a1; p3[seg][qd*4+2]=a2; p3[seg][qd*4+3]=a3;
    }
    __syncthreads();
    // stage B: 24 threads finalize
    if(t<24){
      double a=0.0;
      #pragma unroll
      for(int s=0;s<16;s++) a += p3[s][t];
      sMd[t]=a;
    }
    __syncthreads();
    if(t==0){
      double A0[3][3],A1[3][3],A2[3][3],A3[3][3];
      auto unpackd=[&](const double* s, double M[3][3]){
        M[0][0]=s[0]; M[0][1]=s[1]; M[0][2]=s[3];
        M[1][0]=s[1]; M[1][1]=s[2]; M[1][2]=s[4];
        M[2][0]=s[3]; M[2][1]=s[4]; M[2][2]=s[5];
      };
      unpackd(&sMd[0],A0); unpackd(&sMd[6],A1); unpackd(&sMd[12],A2); unpackd(&sMd[18],A3);

      double L0[3][3], q0[3];
      chol3(A0, L0, q0);
      double T1[3][3], T2[3][3];
      #pragma unroll
      for(int c=0;c<3;c++){
        double col[3]={A1[0][c],A1[1][c],A1[2][c]}, x[3];
        csolve3(L0,q0,col,x);
        T1[0][c]=x[0]; T1[1][c]=x[1]; T1[2][c]=x[2];
      }
      #pragma unroll
      for(int c=0;c<3;c++){
        double col[3]={A2[0][c],A2[1][c],A2[2][c]}, x[3];
        csolve3(L0,q0,col,x);
        T2[0][c]=x[0]; T2[1][c]=x[1]; T2[2][c]=x[2];
      }
      double Sc[3][3];
      #pragma unroll
      for(int i=0;i<3;i++)
        #pragma unroll
        for(int j=0;j<3;j++){
          double s = A3[i][j];
          #pragma unroll
          for(int k=0;k<3;k++) s -= A1[i][k]*T1[k][j] + A2[i][k]*T2[k][j];
          Sc[i][j]=s;
        }
      double Ls[3][3], qs[3];
      chol3(Sc, Ls, qs);

      double v[9];
      #pragma unroll
      for(int i=0;i<9;i++) v[i]=1.0;
      #pragma unroll
      for(int itn=0; itn<2; itn++){
        double a[3]={v[0],v[1],v[2]}, bb[3]={v[3],v[4],v[5]}, cc[3]={v[6],v[7],v[8]};
        double w1[3],w2[3];
        csolve3(L0,q0,a,w1); csolve3(L0,q0,bb,w2);
        double rhs[3];
        #pragma unroll
        for(int j=0;j<3;j++)
          rhs[j] = cc[j] + T1[0][j]*a[0]+T1[1][j]*a[1]+T1[2][j]*a[2]
                         + T2[0][j]*bb[0]+T2[1][j]*bb[1]+T2[2][j]*bb[2];
        double rr[3];
        csolve3(Ls,qs,rhs,rr);
        #pragma unroll
        for(int i=0;i<3;i++){
          v[i]   = w1[i] + T1[i][0]*rr[0]+T1[i][1]*rr[1]+T1[i][2]*rr[2];
          v[3+i] = w2[i] + T2[i][0]*rr[0]+T2[i][1]*rr[1]+T2[i][2]*rr[2];
          v[6+i] = rr[i];
        }
        if(itn==0){
          double mx=0.0;
          #pragma unroll
          for(int i=0;i<9;i++){ double aa=fabs(v[i]); if(aa>mx) mx=aa; }
          double sc = 1.0/(mx + 1e-300);
          #pragma unroll
          for(int i=0;i<9;i++) v[i]*=sc;
        }
      }
      double n2=0.0;
      #pragma unroll
      for(int i=0;i<9;i++) n2 += v[i]*v[i];
      double invn = 1.0/sqrt(n2);
      #pragma unroll
      for(int i=0;i<9;i++) v[i]*=invn;
      #pragma unroll
      for(int j=0;j<9;j++) curHn[j]=(float)v[j];
      if(denorm_now) denorm_h(v, ns1,nm1x,nm1y, ns2,nm2x,nm2y, curH);
    }
    __syncthreads();
  };

  for(int lo=0; lo<5; lo++){
    // iterated DLT: first with 0/1 weights
    #pragma unroll
    for(int q=0;q<8;q++){ int p=t+512*q; wreg[q] = inlb[cur][p] ? 1.0f : 0.0f; }
    DLT(false);
    for(int itp=0; itp<4; itp++){
      // reweight in the NORMALIZED frame with curHn (err_orig = sqrt(e_n+eps*s2^2)/s2)
      float Hn[9];
      #pragma unroll
      for(int j=0;j<9;j++) Hn[j]=curHn[j];
      #pragma unroll
      for(int q=0;q<8;q++){
        int p=t+512*q;
        float zn = Hn[6]*X1[q] + Hn[7]*Y1[q] + Hn[8];
        float zi = 1.0f/zn;
        float dx = (Hn[0]*X1[q] + Hn[1]*Y1[q] + Hn[2])*zi - X2[q];
        float dy = (Hn[3]*X1[q] + Hn[4]*Y1[q] + Hn[5])*zi - Y2[q];
        float err = sqrtf(dx*dx + dy*dy + epsn);
        wreg[q] = inlb[cur][p] ? __expf(-err*wk) : 0.0f;
      }
      DLT(itp==3);   // denormalize only on the round's last DLT
    }
    // verify polished model (original frame — exact reference path)
    float scoreLo;
    {
      float H[9];
      #pragma unroll
      for(int j=0;j<9;j++) H[j]=curH[j];
      int c=0;
      #pragma unroll
      for(int q=0;q<8;q++){
        int p=t+512*q;
        float e = errsq_f(H, U1[q],V1[q],U2[q],V2[q]);
        unsigned char bb = (e <= 2.0f) ? 1 : 0;
        inlb[cur^1][p] = bb;
        c += bb;
      }
      #pragma unroll
      for(int off=32; off>=1; off>>=1) c += __shfl_down(c, off, 64);
      if(lane==0) redi[wv]=c;
      __syncthreads();
      if(t==0){
        int s=0;
        #pragma unroll
        for(int w8=0;w8<8;w8++) s += redi[w8];
        sScore=(float)s;
      }
      __syncthreads();
      scoreLo = sScore;
    }
    bool better = active && (scoreLo > score);
    if(better){
      if(t<9) sModel[t]=curH[t];
      cur ^= 1;
      score = scoreLo;
    }
    active = better;
    __syncthreads();
    if(!active) break;
  }

  // commit state
  if(t<9) stateF[2+t] = sModel[t];
  #pragma unroll
  for(int q=0;q<8;q++){ int p=t+512*q; best_inl[p] = inlb[cur][p] ? 1.0f : 0.0f; }
  if(t==0){
    stateF[0] = score;
    float ratio = floorf(score) / 4096.0f;
    float r2 = ratio*ratio, r4 = r2*r2;
    float q  = 1.0f - r4;
    q = fminf(fmaxf(q, 1e-12f), (float)(1.0 - 1e-12));
    float max_samp = (score >= 4096.0f) ? 1.0f : (logf(0.01f)/logf(q));
    stateF[1] = (((float)((iter+1)*NBATCH)) >= floorf(max_samp)) ? 1.0f : 0.0f;
  }
}

// ---------------- K6: writeout ----------------
__global__ __launch_bounds__(1024) void k_out(const float* stateF, const float* best_inl,
                                              float* __restrict__ out, int out_size){
  const int t = threadIdx.x;
  if(t<9 && t<out_size) out[t] = stateF[2+t];
  #pragma unroll
  for(int q=0;q<4;q++){
    int p = t + 1024*q, o = 9 + p;
    if(o < out_size) out[o] = best_inl[p];
  }
}

// ---------------- host ----------------
static void host_keys(uint32_t* K0h, uint32_t* K1h){
#if JAX_PARTITIONABLE
  for(int i=0;i<10;i++){ uint32_t a,b; tf2x32(0u,42u,0u,(uint32_t)i,a,b); K0h[i]=a; K1h[i]=b; }
#else
  uint32_t arr[20];
  for(int j=0;j<10;j++){ uint32_t a,b; tf2x32(0u,42u,(uint32_t)j,(uint32_t)(j+10),a,b); arr[j]=a; arr[j+10]=b; }
  for(int i=0;i<10;i++){ K0h[i]=arr[2*i]; K1h[i]=arr[2*i+1]; }
#endif
}

extern "C" void kernel_launch(void* const* d_in, const int* in_sizes, int n_in,
                              void* d_out, int out_size, void* d_ws, size_t ws_size,
                              hipStream_t stream) {
  const float* kp1 = (const float*)d_in[0];
  const float* kp2 = (const float*)d_in[1];
  float* out = (float*)d_out;
  float* ws  = (float*)d_ws;

  // ws layout (floats)
  float* stateF   = ws + 0;      // 16: [0]=best_score [1]=done [2..10]=best_model
  float* nrm      = ws + 16;     // 8
  float* best_inl = ws + 32;     // 4096
  float* p1n      = ws + 4128;   // 8192
  float* p2n      = ws + 12320;  // 8192
  float* scores   = ws + 20512;  // 1024
  float* models   = ws + 21536;  // 9216

  uint32_t K0h[10], K1h[10];
  host_keys(K0h, K1h);

  k_init<<<1, 1024, 0, stream>>>(kp1, kp2, stateF, nrm, best_inl, p1n, p2n);
  for(int i=0;i<NIT;i++){
    k_sample_score<<<NBATCH, 256, 0, stream>>>(stateF, K0h[i], K1h[i], kp1, kp2, models, scores);
    k_polish<<<1, 512, 0, stream>>>(stateF, nrm, scores, models, kp1, kp2, p1n, p2n, best_inl, i);
  }
  k_out<<<1, 1024, 0, stream>>>(stateF, best_inl, out, out_size);
}

// Round 7
// 125.156 us; speedup vs baseline: 4.0980x; 1.0096x over previous
//
#include <hip/hip_runtime.h>
#include <cstdint>

#define NPTS   4096
#define NBATCH 1024
#define NIT    10
// coop config
#define CNBLK  256
#define CTPB   256
#define RPB    4      // models per block (coop)
#define PPT    16     // points per thread at 256 threads

// ---------------- threefry2x32 (exact JAX rounds) ----------------
__host__ __device__ inline uint32_t rotl32(uint32_t v, uint32_t r){ return (v<<r)|(v>>(32u-r)); }

__host__ __device__ inline void tf2x32(uint32_t k0,uint32_t k1,uint32_t x0,uint32_t x1,
                                       uint32_t&o0,uint32_t&o1){
  uint32_t ks2 = k0 ^ k1 ^ 0x1BD11BDAu;
  x0 += k0; x1 += k1;
  x0+=x1; x1=rotl32(x1,13); x1^=x0;
  x0+=x1; x1=rotl32(x1,15); x1^=x0;
  x0+=x1; x1=rotl32(x1,26); x1^=x0;
  x0+=x1; x1=rotl32(x1, 6); x1^=x0;
  x0+=k1; x1+=ks2+1u;
  x0+=x1; x1=rotl32(x1,17); x1^=x0;
  x0+=x1; x1=rotl32(x1,29); x1^=x0;
  x0+=x1; x1=rotl32(x1,16); x1^=x0;
  x0+=x1; x1=rotl32(x1,24); x1^=x0;
  x0+=ks2; x1+=k0+2u;
  x0+=x1; x1=rotl32(x1,13); x1^=x0;
  x0+=x1; x1=rotl32(x1,15); x1^=x0;
  x0+=x1; x1=rotl32(x1,26); x1^=x0;
  x0+=x1; x1=rotl32(x1, 6); x1^=x0;
  x0+=k0; x1+=k1+3u;
  x0+=x1; x1=rotl32(x1,17); x1^=x0;
  x0+=x1; x1=rotl32(x1,29); x1^=x0;
  x0+=x1; x1=rotl32(x1,16); x1^=x0;
  x0+=x1; x1=rotl32(x1,24); x1^=x0;
  x0+=k1; x1+=ks2+4u;
  x0+=x1; x1=rotl32(x1,13); x1^=x0;
  x0+=x1; x1=rotl32(x1,15); x1^=x0;
  x0+=x1; x1=rotl32(x1,26); x1^=x0;
  x0+=x1; x1=rotl32(x1, 6); x1^=x0;
  x0+=ks2; x1+=k0+5u;
  o0=x0; o1=x1;
}

// ---------------- shared math helpers ----------------
__device__ inline float errsq_f(const float H[9], float x, float y, float kx, float ky){
  float z  = H[6]*x + H[7]*y + H[8];
  float zi = (fabsf(z) > 1e-8f) ? (1.0f/z) : 1.0f;
  float px = (H[0]*x + H[1]*y + H[2])*zi;
  float py = (H[3]*x + H[4]*y + H[5])*zi;
  float dx = px - kx, dy = py - ky;
  return dx*dx + dy*dy;
}

__device__ inline void denorm_h(const double h[9], double s1, double m1x, double m1y,
                                double s2, double m2x, double m2y, float out[9]){
  double G[3][3];
  #pragma unroll
  for(int r=0;r<3;r++){
    double h0=h[3*r], h1=h[3*r+1], h2=h[3*r+2];
    G[r][0] = h0*s1;
    G[r][1] = h1*s1;
    G[r][2] = -s1*m1x*h0 - s1*m1y*h1 + h2;
  }
  double Hm[3][3];
  double inv2 = 1.0/s2;
  #pragma unroll
  for(int c=0;c<3;c++){
    Hm[0][c] = G[0][c]*inv2 + m2x*G[2][c];
    Hm[1][c] = G[1][c]*inv2 + m2y*G[2][c];
    Hm[2][c] = G[2][c];
  }
  double invd = 1.0/(Hm[2][2] + 1e-8);
  #pragma unroll
  for(int r=0;r<3;r++)
    #pragma unroll
    for(int c=0;c<3;c++)
      out[3*r+c] = (float)(Hm[r][c]*invd);
}

__device__ inline double det3c(double ax,double ay, double bx,double by, double cx,double cy){
  return ax*(by-cy) - bx*(ay-cy) + cx*(ay-by);
}

__device__ inline void h4pt(const double P[4][2], double M[3][3]){
  double c0 = det3c(P[3][0],P[3][1], P[1][0],P[1][1], P[2][0],P[2][1]);
  double c1 = det3c(P[0][0],P[0][1], P[3][0],P[3][1], P[2][0],P[2][1]);
  double c2 = det3c(P[0][0],P[0][1], P[1][0],P[1][1], P[3][0],P[3][1]);
  M[0][0]=c0*P[0][0]; M[0][1]=c1*P[1][0]; M[0][2]=c2*P[2][0];
  M[1][0]=c0*P[0][1]; M[1][1]=c1*P[1][1]; M[1][2]=c2*P[2][1];
  M[2][0]=c0;         M[2][1]=c1;         M[2][2]=c2;
}

__device__ inline void adj3(const double M[3][3], double A[3][3]){
  A[0][0]=M[1][1]*M[2][2]-M[1][2]*M[2][1];
  A[0][1]=M[0][2]*M[2][1]-M[0][1]*M[2][2];
  A[0][2]=M[0][1]*M[1][2]-M[0][2]*M[1][1];
  A[1][0]=M[1][2]*M[2][0]-M[1][0]*M[2][2];
  A[1][1]=M[0][0]*M[2][2]-M[0][2]*M[2][0];
  A[1][2]=M[0][2]*M[1][0]-M[0][0]*M[1][2];
  A[2][0]=M[1][0]*M[2][1]-M[1][1]*M[2][0];
  A[2][1]=M[0][1]*M[2][0]-M[0][0]*M[2][1];
  A[2][2]=M[0][0]*M[1][1]-M[0][1]*M[1][0];
}

__device__ inline void chol3(const double A[3][3], double L[3][3], double r[3]){
  double d0 = A[0][0]; if(d0<1e-280) d0=1e-280;
  double l00 = sqrt(d0); double q0 = 1.0/l00;
  double l10 = A[1][0]*q0, l20 = A[2][0]*q0;
  double d1 = A[1][1]-l10*l10; if(d1<1e-280) d1=1e-280;
  double l11 = sqrt(d1); double q1=1.0/l11;
  double l21 = (A[2][1]-l20*l10)*q1;
  double d2 = A[2][2]-l20*l20-l21*l21; if(d2<1e-280) d2=1e-280;
  double l22 = sqrt(d2); double q2=1.0/l22;
  L[0][0]=l00; L[1][0]=l10; L[1][1]=l11; L[2][0]=l20; L[2][1]=l21; L[2][2]=l22;
  r[0]=q0; r[1]=q1; r[2]=q2;
}
__device__ inline void csolve3(const double L[3][3], const double r[3],
                               const double b[3], double x[3]){
  double y0=b[0]*r[0];
  double y1=(b[1]-L[1][0]*y0)*r[1];
  double y2=(b[2]-L[2][0]*y0-L[2][1]*y1)*r[2];
  x[2]=y2*r[2];
  x[1]=(y1-L[2][1]*x[2])*r[1];
  x[0]=(y0-L[1][0]*x[1]-L[2][0]*x[2])*r[0];
}

__device__ inline void ins4(uint64_t b[4], uint64_t k){
  if(k > b[0]){ b[3]=b[2]; b[2]=b[1]; b[1]=b[0]; b[0]=k; }
  else if(k > b[1]){ b[3]=b[2]; b[2]=b[1]; b[1]=k; }
  else if(k > b[2]){ b[3]=b[2]; b[2]=k; }
  else if(k > b[3]){ b[3]=k; }
}

// the full DLT solve from the 24 reduced sums (f64, serial, one thread)
__device__ inline void solve24(const double* sMd, float curHn[9], float curH[9],
                               bool dnorm, double ns1,double nm1x,double nm1y,
                               double ns2,double nm2x,double nm2y){
  double A0[3][3],A1[3][3],A2[3][3],A3[3][3];
  auto unpackd=[&](const double* s, double M[3][3]){
    M[0][0]=s[0]; M[0][1]=s[1]; M[0][2]=s[3];
    M[1][0]=s[1]; M[1][1]=s[2]; M[1][2]=s[4];
    M[2][0]=s[3]; M[2][1]=s[4]; M[2][2]=s[5];
  };
  unpackd(sMd+0,A0); unpackd(sMd+6,A1); unpackd(sMd+12,A2); unpackd(sMd+18,A3);

  double L0[3][3], q0[3];
  chol3(A0, L0, q0);
  double T1[3][3], T2[3][3];
  #pragma unroll
  for(int c=0;c<3;c++){
    double col[3]={A1[0][c],A1[1][c],A1[2][c]}, x[3];
    csolve3(L0,q0,col,x);
    T1[0][c]=x[0]; T1[1][c]=x[1]; T1[2][c]=x[2];
  }
  #pragma unroll
  for(int c=0;c<3;c++){
    double col[3]={A2[0][c],A2[1][c],A2[2][c]}, x[3];
    csolve3(L0,q0,col,x);
    T2[0][c]=x[0]; T2[1][c]=x[1]; T2[2][c]=x[2];
  }
  double Sc[3][3];
  #pragma unroll
  for(int i=0;i<3;i++)
    #pragma unroll
    for(int j=0;j<3;j++){
      double s = A3[i][j];
      #pragma unroll
      for(int k=0;k<3;k++) s -= A1[i][k]*T1[k][j] + A2[i][k]*T2[k][j];
      Sc[i][j]=s;
    }
  double Ls[3][3], qs[3];
  chol3(Sc, Ls, qs);

  double v[9];
  #pragma unroll
  for(int i=0;i<9;i++) v[i]=1.0;
  #pragma unroll
  for(int itn=0; itn<2; itn++){
    double a[3]={v[0],v[1],v[2]}, bb2[3]={v[3],v[4],v[5]}, cc[3]={v[6],v[7],v[8]};
    double w1[3],w2[3];
    csolve3(L0,q0,a,w1); csolve3(L0,q0,bb2,w2);
    double rhs[3];
    #pragma unroll
    for(int j=0;j<3;j++)
      rhs[j] = cc[j] + T1[0][j]*a[0]+T1[1][j]*a[1]+T1[2][j]*a[2]
                     + T2[0][j]*bb2[0]+T2[1][j]*bb2[1]+T2[2][j]*bb2[2];
    double rr[3];
    csolve3(Ls,qs,rhs,rr);
    #pragma unroll
    for(int i=0;i<3;i++){
      v[i]   = w1[i] + T1[i][0]*rr[0]+T1[i][1]*rr[1]+T1[i][2]*rr[2];
      v[3+i] = w2[i] + T2[i][0]*rr[0]+T2[i][1]*rr[1]+T2[i][2]*rr[2];
      v[6+i] = rr[i];
    }
    if(itn==0){
      double mx=0.0;
      #pragma unroll
      for(int i=0;i<9;i++){ double aa=fabs(v[i]); if(aa>mx) mx=aa; }
      double sc = 1.0/(mx + 1e-300);
      #pragma unroll
      for(int i=0;i<9;i++) v[i]*=sc;
    }
  }
  double n2=0.0;
  #pragma unroll
  for(int i=0;i<9;i++) n2 += v[i]*v[i];
  double invn = 1.0/sqrt(n2);
  #pragma unroll
  for(int i=0;i<9;i++) v[i]*=invn;
  #pragma unroll
  for(int j=0;j<9;j++) curHn[j]=(float)v[j];
  if(dnorm) denorm_h(v, ns1,nm1x,nm1y, ns2,nm2x,nm2y, curH);
}

// the 4-point analytic model + validity (one thread)
__device__ inline void model4(const double P1[4][2], const double P2[4][2],
                              float Hf[9], int* flag){
  const int TRI[4][3] = {{0,1,2},{0,1,3},{0,2,3},{1,2,3}};
  bool valid = true;
  #pragma unroll
  for(int tq=0;tq<4;tq++){
    const int i0=TRI[tq][0], i1=TRI[tq][1], i2=TRI[tq][2];
    double d1 = det3c(P1[i0][0],P1[i0][1], P1[i1][0],P1[i1][1], P1[i2][0],P1[i2][1]);
    double d2 = det3c(P2[i0][0],P2[i0][1], P2[i1][0],P2[i1][1], P2[i2][0],P2[i2][1]);
    int s1 = (d1>0.0)-(d1<0.0), s2 = (d2>0.0)-(d2<0.0);
    if(s1 != s2) valid = false;
  }
  double MA[3][3], MB[3][3], AJ[3][3], H[3][3];
  h4pt(P1, MA); h4pt(P2, MB);
  adj3(MA, AJ);
  #pragma unroll
  for(int i=0;i<3;i++)
    #pragma unroll
    for(int j=0;j<3;j++)
      H[i][j] = MB[i][0]*AJ[0][j] + MB[i][1]*AJ[1][j] + MB[i][2]*AJ[2][j];
  double n2=0.0;
  #pragma unroll
  for(int i=0;i<3;i++)
    #pragma unroll
    for(int j=0;j<3;j++) n2 += H[i][j]*H[i][j];
  double invn = 1.0/sqrt(n2);
  double invd = 1.0/(H[2][2]*invn + 1e-8);
  #pragma unroll
  for(int i=0;i<3;i++)
    #pragma unroll
    for(int j=0;j<3;j++) Hf[3*i+j] = (float)(H[i][j]*invn*invd);
  bool diag_ok = (fminf(fminf(fabsf(Hf[0]),fabsf(Hf[4])),fabsf(Hf[8])) > 1e-4f);
  *flag = (valid && diag_ok) ? 1 : 0;
}

// =====================================================================
// ===============  FALLBACK PATH (round-5, verified)  =================
// =====================================================================
__global__ __launch_bounds__(1024) void k_init(const float* __restrict__ kp1,
                                               const float* __restrict__ kp2,
                                               float* stateF, float* nrm,
                                               float* best_inl, float* p1n, float* p2n){
  __shared__ double red[1024];
  const int t = threadIdx.x;
  auto blk_reduce = [&](double v)->double{
    red[t]=v; __syncthreads();
    for(int off=512; off>=1; off>>=1){ if(t<off) red[t]+=red[t+off]; __syncthreads(); }
    double rr = red[0]; __syncthreads(); return rr;
  };
  double sx1=0, sy1=0, sx2=0, sy2=0;
  #pragma unroll
  for(int q=0;q<4;q++){
    int p = t + 1024*q;
    sx1 += (double)kp1[2*p];   sy1 += (double)kp1[2*p+1];
    sx2 += (double)kp2[2*p];   sy2 += (double)kp2[2*p+1];
  }
  double m1x = blk_reduce(sx1)/(double)NPTS;
  double m1y = blk_reduce(sy1)/(double)NPTS;
  double m2x = blk_reduce(sx2)/(double)NPTS;
  double m2y = blk_reduce(sy2)/(double)NPTS;
  double a1=0, a2=0;
  #pragma unroll
  for(int q=0;q<4;q++){
    int p = t + 1024*q;
    double dx1=(double)kp1[2*p]-m1x, dy1=(double)kp1[2*p+1]-m1y;
    double dx2=(double)kp2[2*p]-m2x, dy2=(double)kp2[2*p+1]-m2y;
    a1 += sqrt(dx1*dx1+dy1*dy1);
    a2 += sqrt(dx2*dx2+dy2*dy2);
  }
  double sc1 = blk_reduce(a1)/(double)NPTS;
  double sc2 = blk_reduce(a2)/(double)NPTS;
  double s1 = 1.4142135623730951/(sc1+1e-8);
  double s2 = 1.4142135623730951/(sc2+1e-8);
  if(t==0){
    nrm[0]=(float)s1; nrm[1]=(float)m1x; nrm[2]=(float)m1y;
    nrm[3]=(float)s2; nrm[4]=(float)m2x; nrm[5]=(float)m2y;
    stateF[0]=4.0f; stateF[1]=0.0f;
    for(int j=0;j<9;j++) stateF[2+j]=0.0f;
  }
  #pragma unroll
  for(int q=0;q<4;q++){
    int p = t + 1024*q;
    p1n[2*p]   = (float)(s1*((double)kp1[2*p]  -m1x));
    p1n[2*p+1] = (float)(s1*((double)kp1[2*p+1]-m1y));
    p2n[2*p]   = (float)(s2*((double)kp2[2*p]  -m2x));
    p2n[2*p+1] = (float)(s2*((double)kp2[2*p+1]-m2y));
    best_inl[p] = 0.0f;
  }
}

__global__ __launch_bounds__(256) void k_sample_score(const float* stateF,
                                                uint32_t key0, uint32_t key1,
                                                const float* __restrict__ kp1,
                                                const float* __restrict__ kp2,
                                                float* __restrict__ models,
                                                float* __restrict__ scores){
  if(stateF[1] != 0.0f) return;
  const int r = blockIdx.x;
  const int t = threadIdx.x;
  __shared__ uint64_t ls[256][4];
  __shared__ float sH[9];
  __shared__ int   sFlag;
  __shared__ int   redi[4];
  uint64_t b[4] = {0ull,0ull,0ull,0ull};
  #pragma unroll
  for(int j=0;j<16;j++){
    int c = t*16 + j;
    uint32_t f = (uint32_t)(r*NPTS + c);
    uint32_t a0,a1;
    tf2x32(key0,key1, 0u, f, a0,a1);
    uint32_t bits = a0 ^ a1;
    uint64_t v = (uint64_t)((bits>>9) + 1u);
    uint64_t key = (v<<12) | (uint64_t)(4095 - c);
    ins4(b, key);
  }
  ls[t][0]=b[0]; ls[t][1]=b[1]; ls[t][2]=b[2]; ls[t][3]=b[3];
  __syncthreads();
  for(int off=128; off>=1; off>>=1){
    if(t < off){
      uint64_t o0=ls[t+off][0], o1=ls[t+off][1], o2=ls[t+off][2], o3=ls[t+off][3];
      ins4(b,o0); ins4(b,o1); ins4(b,o2); ins4(b,o3);
      ls[t][0]=b[0]; ls[t][1]=b[1]; ls[t][2]=b[2]; ls[t][3]=b[3];
    }
    __syncthreads();
  }
  if(t==0){
    double P1[4][2], P2[4][2];
    #pragma unroll
    for(int k=0;k<4;k++){
      int id = 4095 - (int)(b[k] & 0xFFFull);
      P1[k][0]=(double)kp1[2*id]; P1[k][1]=(double)kp1[2*id+1];
      P2[k][0]=(double)kp2[2*id]; P2[k][1]=(double)kp2[2*id+1];
    }
    float Hf[9]; int fl;
    model4(P1,P2,Hf,&fl);
    #pragma unroll
    for(int j=0;j<9;j++){ models[r*9+j]=Hf[j]; sH[j]=Hf[j]; }
    sFlag = fl;
  }
  __syncthreads();
  float H[9];
  #pragma unroll
  for(int j=0;j<9;j++) H[j]=sH[j];
  int cnt=0;
  #pragma unroll
  for(int j=0;j<16;j++){
    int p = t + 256*j;
    float e = errsq_f(H, kp1[2*p], kp1[2*p+1], kp2[2*p], kp2[2*p+1]);
    cnt += (e <= 2.0f) ? 1 : 0;
  }
  #pragma unroll
  for(int off=32; off>=1; off>>=1) cnt += __shfl_down(cnt, off, 64);
  if((t&63)==0) redi[t>>6]=cnt;
  __syncthreads();
  if(t==0) scores[r] = sFlag ? (float)(redi[0]+redi[1]+redi[2]+redi[3]) : -1.0f;
}

__global__ __launch_bounds__(512) void k_polish(float* stateF, const float* nrm,
                                                const float* __restrict__ scores,
                                                const float* __restrict__ models,
                                                const float* __restrict__ kp1,
                                                const float* __restrict__ kp2,
                                                const float* __restrict__ p1n,
                                                const float* __restrict__ p2n,
                                                float* __restrict__ best_inl,
                                                int iter){
  if(stateF[1] != 0.0f) return;
  const int t = threadIdx.x;
  const int lane = t & 63, wv = t >> 6;
  __shared__ float  p2b[512][28];
  __shared__ double p3[16][25];
  __shared__ double sMd[24];
  __shared__ uint64_t redu[8];
  __shared__ int   redi[8];
  __shared__ float sScore;
  __shared__ float sModel[9];
  __shared__ float curHn[9];
  __shared__ float curH[9];
  __shared__ unsigned char inlb[2][NPTS];

  {
    float sA = scores[t], sB = scores[t+512];
    uint64_t kA = ((uint64_t)(uint32_t)(int)(sA + 2.0f) << 12) | (uint64_t)(1023 - t);
    uint64_t kB = ((uint64_t)(uint32_t)(int)(sB + 2.0f) << 12) | (uint64_t)(1023 - (t+512));
    uint64_t k = (kA >= kB) ? kA : kB;
    #pragma unroll
    for(int off=32; off>=1; off>>=1){
      uint64_t o = __shfl_down(k, off, 64);
      if(o > k) k = o;
    }
    if(lane==0) redu[wv]=k;
  }
  __syncthreads();
  if(t==0){
    uint64_t m=redu[0];
    #pragma unroll
    for(int w8=1;w8<8;w8++) if(redu[w8]>m) m=redu[w8];
    redu[0]=m;
  }
  __syncthreads();
  const int bi = 1023 - (int)(redu[0] & 0xFFFull);
  const float selScore = (float)((int)(redu[0] >> 12)) - 2.0f;

  const float bestScore = stateF[0];
  const bool improve = (selScore > bestScore);
  if(!improve) return;

  if(t<9) sModel[t] = models[bi*9+t];
  __syncthreads();

  float U1[8],V1[8],U2[8],V2[8],X1[8],Y1[8],X2[8],Y2[8];
  #pragma unroll
  for(int q=0;q<8;q++){
    int p = t + 512*q;
    U1[q]=kp1[2*p]; V1[q]=kp1[2*p+1];
    U2[q]=kp2[2*p]; V2[q]=kp2[2*p+1];
    X1[q]=p1n[2*p]; Y1[q]=p1n[2*p+1];
    X2[q]=p2n[2*p]; Y2[q]=p2n[2*p+1];
  }
  {
    float H[9];
    #pragma unroll
    for(int j=0;j<9;j++) H[j]=sModel[j];
    #pragma unroll
    for(int q=0;q<8;q++){
      int p = t + 512*q;
      float e = errsq_f(H, U1[q],V1[q],U2[q],V2[q]);
      inlb[0][p] = (e <= 2.0f) ? 1 : 0;
    }
  }
  __syncthreads();

  int cur = 0;
  float score = selScore;
  bool active = true;
  float wreg[8];

  const double ns1=(double)nrm[0], nm1x=(double)nrm[1], nm1y=(double)nrm[2];
  const double ns2=(double)nrm[3], nm2x=(double)nrm[4], nm2y=(double)nrm[5];
  const float s2f  = nrm[3];
  const float epsn = 1e-8f*s2f*s2f;
  const float wk   = 1.0f/(18.0f*s2f);

  auto DLT = [&](bool denorm_now){
    float part[24];
    #pragma unroll
    for(int k=0;k<24;k++) part[k]=0.0f;
    #pragma unroll
    for(int q=0;q<8;q++){
      float w = wreg[q];
      float x=X1[q], y=Y1[q], x2=X2[q], y2=Y2[q];
      float wx = w*x, wy = w*y;
      float m0=wx*x, m1=wx*y, m2=wy*y;
      float s3 = x2*x2 + y2*y2;
      part[0]+=m0; part[1]+=m1; part[2]+=m2; part[3]+=wx; part[4]+=wy; part[5]+=w;
      part[6]+=x2*m0; part[7]+=x2*m1; part[8]+=x2*m2; part[9]+=x2*wx; part[10]+=x2*wy; part[11]+=x2*w;
      part[12]+=y2*m0; part[13]+=y2*m1; part[14]+=y2*m2; part[15]+=y2*wx; part[16]+=y2*wy; part[17]+=y2*w;
      part[18]+=s3*m0; part[19]+=s3*m1; part[20]+=s3*m2; part[21]+=s3*wx; part[22]+=s3*wy; part[23]+=s3*w;
    }
    float4* rowp = reinterpret_cast<float4*>(&p2b[t][0]);
    rowp[0]=make_float4(part[0],part[1],part[2],part[3]);
    rowp[1]=make_float4(part[4],part[5],part[6],part[7]);
    rowp[2]=make_float4(part[8],part[9],part[10],part[11]);
    rowp[3]=make_float4(part[12],part[13],part[14],part[15]);
    rowp[4]=make_float4(part[16],part[17],part[18],part[19]);
    rowp[5]=make_float4(part[20],part[21],part[22],part[23]);
    __syncthreads();
    if(t<96){
      int qd = t%6, seg = t/6;
      double a0=0,a1=0,a2=0,a3=0;
      #pragma unroll
      for(int i=0;i<32;i++){
        float4 v = *reinterpret_cast<const float4*>(&p2b[seg*32+i][qd*4]);
        a0+=(double)v.x; a1+=(double)v.y; a2+=(double)v.z; a3+=(double)v.w;
      }
      p3[seg][qd*4+0]=a0; p3[seg][qd*4+1]=a1; p3[seg][qd*4+2]=a2; p3[seg][qd*4+3]=a3;
    }
    __syncthreads();
    if(t<24){
      double a=0.0;
      #pragma unroll
      for(int s=0;s<16;s++) a += p3[s][t];
      sMd[t]=a;
    }
    __syncthreads();
    if(t==0) solve24(sMd, curHn, curH, denorm_now, ns1,nm1x,nm1y, ns2,nm2x,nm2y);
    __syncthreads();
  };

  for(int lo=0; lo<5; lo++){
    #pragma unroll
    for(int q=0;q<8;q++){ int p=t+512*q; wreg[q] = inlb[cur][p] ? 1.0f : 0.0f; }
    DLT(false);
    for(int itp=0; itp<4; itp++){
      float Hn[9];
      #pragma unroll
      for(int j=0;j<9;j++) Hn[j]=curHn[j];
      #pragma unroll
      for(int q=0;q<8;q++){
        int p=t+512*q;
        float zn = Hn[6]*X1[q] + Hn[7]*Y1[q] + Hn[8];
        float zi = 1.0f/zn;
        float dx = (Hn[0]*X1[q] + Hn[1]*Y1[q] + Hn[2])*zi - X2[q];
        float dy = (Hn[3]*X1[q] + Hn[4]*Y1[q] + Hn[5])*zi - Y2[q];
        float err = sqrtf(dx*dx + dy*dy + epsn);
        wreg[q] = inlb[cur][p] ? __expf(-err*wk) : 0.0f;
      }
      DLT(itp==3);
    }
    float scoreLo;
    {
      float H[9];
      #pragma unroll
      for(int j=0;j<9;j++) H[j]=curH[j];
      int c=0;
      #pragma unroll
      for(int q=0;q<8;q++){
        int p=t+512*q;
        float e = errsq_f(H, U1[q],V1[q],U2[q],V2[q]);
        unsigned char bb = (e <= 2.0f) ? 1 : 0;
        inlb[cur^1][p] = bb;
        c += bb;
      }
      #pragma unroll
      for(int off=32; off>=1; off>>=1) c += __shfl_down(c, off, 64);
      if(lane==0) redi[wv]=c;
      __syncthreads();
      if(t==0){
        int s=0;
        #pragma unroll
        for(int w8=0;w8<8;w8++) s += redi[w8];
        sScore=(float)s;
      }
      __syncthreads();
      scoreLo = sScore;
    }
    bool better = active && (scoreLo > score);
    if(better){
      if(t<9) sModel[t]=curH[t];
      cur ^= 1;
      score = scoreLo;
    }
    active = better;
    __syncthreads();
    if(!active) break;
  }

  if(t<9) stateF[2+t] = sModel[t];
  #pragma unroll
  for(int q=0;q<8;q++){ int p=t+512*q; best_inl[p] = inlb[cur][p] ? 1.0f : 0.0f; }
  if(t==0){
    stateF[0] = score;
    float ratio = floorf(score) / 4096.0f;
    float r2 = ratio*ratio, r4 = r2*r2;
    float q  = 1.0f - r4;
    q = fminf(fmaxf(q, 1e-12f), (float)(1.0 - 1e-12));
    float max_samp = (score >= 4096.0f) ? 1.0f : (logf(0.01f)/logf(q));
    stateF[1] = (((float)((iter+1)*NBATCH)) >= floorf(max_samp)) ? 1.0f : 0.0f;
  }
}

__global__ __launch_bounds__(1024) void k_out(const float* stateF, const float* best_inl,
                                              float* __restrict__ out, int out_size){
  const int t = threadIdx.x;
  if(t<9 && t<out_size) out[t] = stateF[2+t];
  #pragma unroll
  for(int q=0;q<4;q++){
    int p = t + 1024*q, o = 9 + p;
    if(o < out_size) out[o] = best_inl[p];
  }
}

// =====================================================================
// ===============  COOPERATIVE PATH (hand-rolled barrier) =============
// =====================================================================
struct ShSample {
  unsigned long long ls[CTPB][4];
  float sH[9];
  int   sFlag;
  int   redi[4];
};
struct ShPolish {
  float  p2b[CTPB][28];
  double p3[16][25];
  double sMd[24];
  unsigned long long redu[4];
  int    redi[4];
  float  sScore;
  float  sModel[9];
  float  curHn[9];
  float  curH[9];
};
struct ShInit {
  double arr[CTPB][4];
  double res[4];
};
union ShAll { ShSample s; ShPolish p; ShInit i; };

// generation grid barrier on workspace memory (zeroed host-side each call)
__device__ inline void gridbar(uint32_t* cnt, uint32_t* gen, uint32_t nblk){
  __threadfence();
  __syncthreads();
  if(threadIdx.x==0){
    uint32_t g = __hip_atomic_load(gen, __ATOMIC_ACQUIRE, __HIP_MEMORY_SCOPE_AGENT);
    uint32_t a = __hip_atomic_fetch_add(cnt, 1u, __ATOMIC_ACQ_REL, __HIP_MEMORY_SCOPE_AGENT);
    if(a == nblk-1u){
      __hip_atomic_store(cnt, 0u, __ATOMIC_RELAXED, __HIP_MEMORY_SCOPE_AGENT);
      __hip_atomic_store(gen, g+1u, __ATOMIC_RELEASE, __HIP_MEMORY_SCOPE_AGENT);
    }else{
      while(__hip_atomic_load(gen, __ATOMIC_ACQUIRE, __HIP_MEMORY_SCOPE_AGENT) == g){
        __builtin_amdgcn_s_sleep(2);
      }
    }
  }
  __syncthreads();
  __threadfence();
}

__global__ __launch_bounds__(CTPB) void k_all(const float* __restrict__ kp1,
                                              const float* __restrict__ kp2,
                                              float* __restrict__ out, int out_size,
                                              float* __restrict__ ws){
  const int b = blockIdx.x;
  const int t = threadIdx.x;
  const int lane = t & 63, wv = t >> 6;

  float* stateF   = ws + 0;
  float* nrm      = ws + 16;
  float* best_inl = ws + 32;
  float* scores   = ws + 20512;
  float* models   = ws + 21536;
  uint32_t* barw  = (uint32_t*)(ws + 30752);  // [0]=cnt [1]=gen, memset to 0 each call

  __shared__ ShAll sh;

  // ---------- init (block 0) ----------
  if(b == 0){
    double s0=0,s1=0,s2=0,s3=0;
    #pragma unroll
    for(int q=0;q<PPT;q++){
      int p = t + CTPB*q;
      float2 a = ((const float2*)kp1)[p];
      float2 c = ((const float2*)kp2)[p];
      s0 += (double)a.x; s1 += (double)a.y; s2 += (double)c.x; s3 += (double)c.y;
      best_inl[p] = 0.0f;
    }
    sh.i.arr[t][0]=s0; sh.i.arr[t][1]=s1; sh.i.arr[t][2]=s2; sh.i.arr[t][3]=s3;
    __syncthreads();
    if(t < 4){
      double a = 0;
      for(int r=0;r<CTPB;r++) a += sh.i.arr[r][t];
      sh.i.res[t] = a / (double)NPTS;
    }
    __syncthreads();
    const double m1x = sh.i.res[0], m1y = sh.i.res[1];
    const double m2x = sh.i.res[2], m2y = sh.i.res[3];
    __syncthreads();
    double a1=0, a2=0;
    #pragma unroll
    for(int q=0;q<PPT;q++){
      int p = t + CTPB*q;
      float2 a = ((const float2*)kp1)[p];
      float2 c = ((const float2*)kp2)[p];
      double dx1=(double)a.x-m1x, dy1=(double)a.y-m1y;
      double dx2=(double)c.x-m2x, dy2=(double)c.y-m2y;
      a1 += sqrt(dx1*dx1+dy1*dy1);
      a2 += sqrt(dx2*dx2+dy2*dy2);
    }
    sh.i.arr[t][0]=a1; sh.i.arr[t][1]=a2;
    __syncthreads();
    if(t < 2){
      double a=0;
      for(int r=0;r<CTPB;r++) a += sh.i.arr[r][t];
      sh.i.res[t] = a / (double)NPTS;
    }
    __syncthreads();
    if(t==0){
      double sc1 = sh.i.res[0], sc2 = sh.i.res[1];
      double s1d = 1.4142135623730951/(sc1+1e-8);
      double s2d = 1.4142135623730951/(sc2+1e-8);
      nrm[0]=(float)s1d; nrm[1]=(float)m1x; nrm[2]=(float)m1y;
      nrm[3]=(float)s2d; nrm[4]=(float)m2x; nrm[5]=(float)m2y;
      stateF[0]=4.0f;
      __hip_atomic_store(&stateF[1], 0.0f, __ATOMIC_RELEASE, __HIP_MEMORY_SCOPE_AGENT);
      for(int j=0;j<9;j++) stateF[2+j]=0.0f;
    }
    __syncthreads();
  }

  // ---------- iteration loop ----------
  for(int i=0;i<NIT;i++){
    if(i > 0){
      float dn = __hip_atomic_load(&stateF[1], __ATOMIC_ACQUIRE, __HIP_MEMORY_SCOPE_AGENT);
      if(dn != 0.0f) break;   // uniform (post-barrier value)
    }
    uint32_t key0, key1;
    tf2x32(0u,42u,0u,(uint32_t)i,key0,key1);

    // ---- sample + model + score ----
    for(int m=0;m<RPB;m++){
      const int r = b*RPB + m;
      uint64_t bb[4] = {0ull,0ull,0ull,0ull};
      #pragma unroll
      for(int j=0;j<16;j++){
        int c = t*16 + j;
        uint32_t f = (uint32_t)(r*NPTS + c);
        uint32_t a0,a1;
        tf2x32(key0,key1, 0u, f, a0,a1);
        uint32_t bits = a0 ^ a1;
        uint64_t v = (uint64_t)((bits>>9) + 1u);
        uint64_t kk = (v<<12) | (uint64_t)(4095 - c);
        ins4(bb, kk);
      }
      sh.s.ls[t][0]=bb[0]; sh.s.ls[t][1]=bb[1]; sh.s.ls[t][2]=bb[2]; sh.s.ls[t][3]=bb[3];
      __syncthreads();
      for(int off=128; off>=1; off>>=1){
        if(t < off){
          uint64_t o0=sh.s.ls[t+off][0], o1=sh.s.ls[t+off][1];
          uint64_t o2=sh.s.ls[t+off][2], o3=sh.s.ls[t+off][3];
          ins4(bb,o0); ins4(bb,o1); ins4(bb,o2); ins4(bb,o3);
          sh.s.ls[t][0]=bb[0]; sh.s.ls[t][1]=bb[1]; sh.s.ls[t][2]=bb[2]; sh.s.ls[t][3]=bb[3];
        }
        __syncthreads();
      }
      if(t==0){
        double P1[4][2], P2[4][2];
        #pragma unroll
        for(int k=0;k<4;k++){
          int id = 4095 - (int)(bb[k] & 0xFFFull);
          P1[k][0]=(double)kp1[2*id]; P1[k][1]=(double)kp1[2*id+1];
          P2[k][0]=(double)kp2[2*id]; P2[k][1]=(double)kp2[2*id+1];
        }
        float Hf[9]; int fl;
        model4(P1,P2,Hf,&fl);
        #pragma unroll
        for(int j=0;j<9;j++){ models[r*9+j]=Hf[j]; sh.s.sH[j]=Hf[j]; }
        sh.s.sFlag = fl;
      }
      __syncthreads();
      float H[9];
      #pragma unroll
      for(int j=0;j<9;j++) H[j]=sh.s.sH[j];
      int cnt=0;
      #pragma unroll
      for(int j=0;j<PPT;j++){
        int p = t + CTPB*j;
        float2 a = ((const float2*)kp1)[p];
        float2 c = ((const float2*)kp2)[p];
        float e = errsq_f(H, a.x, a.y, c.x, c.y);
        cnt += (e <= 2.0f) ? 1 : 0;
      }
      #pragma unroll
      for(int off=32; off>=1; off>>=1) cnt += __shfl_down(cnt, off, 64);
      if(lane==0) sh.s.redi[wv]=cnt;
      __syncthreads();
      if(t==0) scores[r] = sh.s.sFlag ?
          (float)(sh.s.redi[0]+sh.s.redi[1]+sh.s.redi[2]+sh.s.redi[3]) : -1.0f;
      __syncthreads();
    }
    gridbar(&barw[0], &barw[1], (uint32_t)gridDim.x);

    // ---- polish (block 0) ----
    if(b==0){
      uint64_t k = 0;
      #pragma unroll
      for(int c4=0;c4<4;c4++){
        int r = t + 256*c4;
        float sv = __hip_atomic_load(&scores[r], __ATOMIC_ACQUIRE, __HIP_MEMORY_SCOPE_AGENT);
        uint64_t key = ((uint64_t)(uint32_t)(int)(sv + 2.0f) << 12) | (uint64_t)(1023 - r);
        if(key > k) k = key;
      }
      #pragma unroll
      for(int off=32; off>=1; off>>=1){
        uint64_t o = __shfl_down(k, off, 64);
        if(o > k) k = o;
      }
      if(lane==0) sh.p.redu[wv]=k;
      __syncthreads();
      if(t==0){
        uint64_t mm=sh.p.redu[0];
        #pragma unroll
        for(int w8=1;w8<4;w8++) if(sh.p.redu[w8]>mm) mm=sh.p.redu[w8];
        sh.p.redu[0]=mm;
      }
      __syncthreads();
      const int bi = 1023 - (int)(sh.p.redu[0] & 0xFFFull);
      const float selScore = (float)((int)(sh.p.redu[0] >> 12)) - 2.0f;
      const bool improve = (selScore > stateF[0]);

      if(improve){
        if(t<9) sh.p.sModel[t] =
            __hip_atomic_load(&models[bi*9+t], __ATOMIC_ACQUIRE, __HIP_MEMORY_SCOPE_AGENT);
        __syncthreads();

        float U1[PPT],V1[PPT],U2[PPT],V2[PPT];
        #pragma unroll
        for(int q=0;q<PPT;q++){
          int p = t + CTPB*q;
          float2 a = ((const float2*)kp1)[p];
          float2 c = ((const float2*)kp2)[p];
          U1[q]=a.x; V1[q]=a.y; U2[q]=c.x; V2[q]=c.y;
        }
        const float s1f=nrm[0], m1xf=nrm[1], m1yf=nrm[2];
        const float s2f=nrm[3], m2xf=nrm[4], m2yf=nrm[5];
        const float tx1=-(s1f*m1xf), ty1=-(s1f*m1yf);
        const float tx2=-(s2f*m2xf), ty2=-(s2f*m2yf);
        const double ns1=(double)s1f, nm1x=(double)m1xf, nm1y=(double)m1yf;
        const double ns2=(double)s2f, nm2x=(double)m2xf, nm2y=(double)m2yf;
        const float epsn = 1e-8f*s2f*s2f;
        const float wk   = 1.0f/(18.0f*s2f);

        uint32_t cm = 0;
        {
          float H[9];
          #pragma unroll
          for(int j=0;j<9;j++) H[j]=sh.p.sModel[j];
          #pragma unroll
          for(int q=0;q<PPT;q++){
            float e = errsq_f(H, U1[q],V1[q],U2[q],V2[q]);
            cm |= (e <= 2.0f ? 1u : 0u) << q;
          }
        }

        float score = selScore;
        bool active = true;
        float wreg[PPT];

        auto DLT = [&](bool dnorm){
          float part[24];
          #pragma unroll
          for(int kk=0;kk<24;kk++) part[kk]=0.0f;
          #pragma unroll
          for(int q=0;q<PPT;q++){
            float w = wreg[q];
            float x  = fmaf(s1f, U1[q], tx1), y  = fmaf(s1f, V1[q], ty1);
            float x2 = fmaf(s2f, U2[q], tx2), y2 = fmaf(s2f, V2[q], ty2);
            float wx = w*x, wy = w*y;
            float m0=wx*x, m1=wx*y, m2=wy*y;
            float s3 = x2*x2 + y2*y2;
            part[0]+=m0; part[1]+=m1; part[2]+=m2; part[3]+=wx; part[4]+=wy; part[5]+=w;
            part[6]+=x2*m0; part[7]+=x2*m1; part[8]+=x2*m2; part[9]+=x2*wx; part[10]+=x2*wy; part[11]+=x2*w;
            part[12]+=y2*m0; part[13]+=y2*m1; part[14]+=y2*m2; part[15]+=y2*wx; part[16]+=y2*wy; part[17]+=y2*w;
            part[18]+=s3*m0; part[19]+=s3*m1; part[20]+=s3*m2; part[21]+=s3*wx; part[22]+=s3*wy; part[23]+=s3*w;
          }
          float4* rowp = reinterpret_cast<float4*>(&sh.p.p2b[t][0]);
          rowp[0]=make_float4(part[0],part[1],part[2],part[3]);
          rowp[1]=make_float4(part[4],part[5],part[6],part[7]);
          rowp[2]=make_float4(part[8],part[9],part[10],part[11]);
          rowp[3]=make_float4(part[12],part[13],part[14],part[15]);
          rowp[4]=make_float4(part[16],part[17],part[18],part[19]);
          rowp[5]=make_float4(part[20],part[21],part[22],part[23]);
          __syncthreads();
          if(t<96){
            int qd = t%6, seg = t/6;
            double a0=0,a1=0,a2=0,a3=0;
            #pragma unroll
            for(int rr=0;rr<16;rr++){
              float4 v = *reinterpret_cast<const float4*>(&sh.p.p2b[seg*16+rr][qd*4]);
              a0+=(double)v.x; a1+=(double)v.y; a2+=(double)v.z; a3+=(double)v.w;
            }
            sh.p.p3[seg][qd*4+0]=a0; sh.p.p3[seg][qd*4+1]=a1;
            sh.p.p3[seg][qd*4+2]=a2; sh.p.p3[seg][qd*4+3]=a3;
          }
          __syncthreads();
          if(t<24){
            double a=0.0;
            #pragma unroll
            for(int s=0;s<16;s++) a += sh.p.p3[s][t];
            sh.p.sMd[t]=a;
          }
          __syncthreads();
          if(t==0) solve24(sh.p.sMd, sh.p.curHn, sh.p.curH, dnorm,
                           ns1,nm1x,nm1y, ns2,nm2x,nm2y);
          __syncthreads();
        };

        for(int lo=0; lo<5; lo++){
          #pragma unroll
          for(int q=0;q<PPT;q++) wreg[q] = ((cm>>q)&1u) ? 1.0f : 0.0f;
          DLT(false);
          for(int itp=0; itp<4; itp++){
            float Hn[9];
            #pragma unroll
            for(int j=0;j<9;j++) Hn[j]=sh.p.curHn[j];
            #pragma unroll
            for(int q=0;q<PPT;q++){
              float x  = fmaf(s1f, U1[q], tx1), y  = fmaf(s1f, V1[q], ty1);
              float x2 = fmaf(s2f, U2[q], tx2), y2 = fmaf(s2f, V2[q], ty2);
              float zn = Hn[6]*x + Hn[7]*y + Hn[8];
              float zi = 1.0f/zn;
              float dx = (Hn[0]*x + Hn[1]*y + Hn[2])*zi - x2;
              float dy = (Hn[3]*x + Hn[4]*y + Hn[5])*zi - y2;
              float err = sqrtf(dx*dx + dy*dy + epsn);
              wreg[q] = ((cm>>q)&1u) ? __expf(-err*wk) : 0.0f;
            }
            DLT(itp==3);
          }
          float H[9];
          #pragma unroll
          for(int j=0;j<9;j++) H[j]=sh.p.curH[j];
          uint32_t nmv = 0;
          #pragma unroll
          for(int q=0;q<PPT;q++){
            float e = errsq_f(H, U1[q],V1[q],U2[q],V2[q]);
            nmv |= (e <= 2.0f ? 1u : 0u) << q;
          }
          int c = __popc(nmv);
          #pragma unroll
          for(int off=32; off>=1; off>>=1) c += __shfl_down(c, off, 64);
          if(lane==0) sh.p.redi[wv]=c;
          __syncthreads();
          if(t==0) sh.p.sScore = (float)(sh.p.redi[0]+sh.p.redi[1]+sh.p.redi[2]+sh.p.redi[3]);
          __syncthreads();
          float scoreLo = sh.p.sScore;
          bool better = active && (scoreLo > score);
          if(better){
            if(t<9) sh.p.sModel[t]=sh.p.curH[t];
            cm = nmv;
            score = scoreLo;
          }
          active = better;
          __syncthreads();
          if(!active) break;
        }

        if(t<9) stateF[2+t] = sh.p.sModel[t];
        #pragma unroll
        for(int q=0;q<PPT;q++){
          int p = t + CTPB*q;
          best_inl[p] = ((cm>>q)&1u) ? 1.0f : 0.0f;
        }
        if(t==0){
          stateF[0] = score;
          float ratio = floorf(score) / 4096.0f;
          float r2 = ratio*ratio, r4 = r2*r2;
          float q  = 1.0f - r4;
          q = fminf(fmaxf(q, 1e-12f), (float)(1.0 - 1e-12));
          float max_samp = (score >= 4096.0f) ? 1.0f : (logf(0.01f)/logf(q));
          float dn = (((float)((i+1)*NBATCH)) >= floorf(max_samp)) ? 1.0f : 0.0f;
          __hip_atomic_store(&stateF[1], dn, __ATOMIC_RELEASE, __HIP_MEMORY_SCOPE_AGENT);
        }
      }
    }
    gridbar(&barw[0], &barw[1], (uint32_t)gridDim.x);
  }

  // ---------- writeout (block 0) ----------
  if(b==0){
    if(t<9 && t<out_size) out[t] = stateF[2+t];
    #pragma unroll
    for(int q=0;q<PPT;q++){
      int p = t + CTPB*q, o = 9 + p;
      if(o < out_size) out[o] = best_inl[p];
    }
  }
}

// ---------------- host ----------------
extern "C" void kernel_launch(void* const* d_in, const int* in_sizes, int n_in,
                              void* d_out, int out_size, void* d_ws, size_t ws_size,
                              hipStream_t stream) {
  const float* kp1 = (const float*)d_in[0];
  const float* kp2 = (const float*)d_in[1];
  float* out = (float*)d_out;
  float* ws  = (float*)d_ws;

  // ws layout (floats) — shared by both paths
  float* stateF   = ws + 0;
  float* nrm      = ws + 16;
  float* best_inl = ws + 32;
  float* p1n      = ws + 4128;
  float* p2n      = ws + 12320;
  float* scores   = ws + 20512;
  float* models   = ws + 21536;
  void*  barw     = (void*)(ws + 30752);

  // host-side capability gating (pure queries — capture-safe, deterministic)
  int dev = 0; (void)hipGetDevice(&dev);
  int coop = 0;
  (void)hipDeviceGetAttribute(&coop, hipDeviceAttributeCooperativeLaunch, dev);
  int maxb = 0;
  if(coop)
    (void)hipOccupancyMaxActiveBlocksPerMultiprocessor(&maxb, k_all, CTPB, 0);

  bool coop_ok = false;
  if(coop && maxb >= 1){
    (void)hipMemsetAsync(barw, 0, 16, stream);   // zero barrier words
    void* args[] = { (void*)&kp1, (void*)&kp2, (void*)&out, (void*)&out_size, (void*)&ws };
    hipError_t e = hipLaunchCooperativeKernel((void*)k_all, dim3(CNBLK), dim3(CTPB),
                                              args, 0, stream);
    if(e == hipSuccess) coop_ok = true;
    else (void)hipGetLastError();   // clear sticky error, take fallback
  }

  if(!coop_ok){
    uint32_t K0h[10], K1h[10];
    for(int i=0;i<10;i++){ uint32_t a,b; tf2x32(0u,42u,0u,(uint32_t)i,a,b); K0h[i]=a; K1h[i]=b; }
    k_init<<<1, 1024, 0, stream>>>(kp1, kp2, stateF, nrm, best_inl, p1n, p2n);
    for(int i=0;i<NIT;i++){
      k_sample_score<<<NBATCH, 256, 0, stream>>>(stateF, K0h[i], K1h[i], kp1, kp2, models, scores);
      k_polish<<<1, 512, 0, stream>>>(stateF, nrm, scores, models, kp1, kp2, p1n, p2n, best_inl, i);
    }
    k_out<<<1, 1024, 0, stream>>>(stateF, best_inl, out, out_size);
  }
}